// Round 6
// baseline (417.780 us; speedup 1.0000x reference)
//
#include <hip/hip_runtime.h>
#include <hip/hip_bf16.h>
#include <math.h>

// Problem constants (B=4, T=1024, C=768, E=8, K=2)
#define N_TOK 4096
#define CDIM  768
#define E_EXP 8
#define CAPC  2048
#define HDIM  3072   // 4*C

typedef __attribute__((ext_vector_type(8))) short short8;
typedef __attribute__((ext_vector_type(4))) float floatx4;

#define VMCNT(n) asm volatile("s_waitcnt vmcnt(" #n ")" ::: "memory")
#define LGKM(n)  asm volatile("s_waitcnt lgkmcnt(" #n ")" ::: "memory")
#define SB0()    __builtin_amdgcn_sched_barrier(0)

static __device__ __forceinline__ unsigned short f2bf(float f) {
  __hip_bfloat16 h = __float2bfloat16(f);
  return __builtin_bit_cast(unsigned short, h);
}

// ---------------------------------------------------------------------------
// K1: transpose + f32->bf16 convert.  in: [E][R][Cc] f32 -> out: [E][Cc][R] bf16
// ---------------------------------------------------------------------------
__global__ __launch_bounds__(256)
void transpose_convert(const float* __restrict__ in, __hip_bfloat16* __restrict__ out,
                       int R, int Cc)
{
  __shared__ float tile[32][33];
  const int e  = blockIdx.z;
  const int c0 = blockIdx.x * 32;
  const int r0 = blockIdx.y * 32;
  const float* ie = in + (size_t)e * R * Cc;
  __hip_bfloat16* oe = out + (size_t)e * Cc * R;
  const int t = threadIdx.x;
  {
    const int r = t >> 3, c = (t & 7) * 4;
    const float4 v = *(const float4*)(ie + (size_t)(r0 + r) * Cc + c0 + c);
    tile[r][c + 0] = v.x; tile[r][c + 1] = v.y; tile[r][c + 2] = v.z; tile[r][c + 3] = v.w;
  }
  __syncthreads();
  {
    const int cc = t >> 3, rr = (t & 7) * 4;
    ushort4 o;
    o.x = f2bf(tile[rr + 0][cc]);
    o.y = f2bf(tile[rr + 1][cc]);
    o.z = f2bf(tile[rr + 2][cc]);
    o.w = f2bf(tile[rr + 3][cc]);
    *(ushort4*)((unsigned short*)oe + (size_t)(c0 + cc) * R + r0 + rr) = o;
  }
}

// ---------------------------------------------------------------------------
// K2: router — logits = x @ w_g^T, top-2 + softmax over the two kept logits.
// ---------------------------------------------------------------------------
__global__ __launch_bounds__(256)
void router_kernel(const float* __restrict__ x, const float* __restrict__ wg,
                   int* __restrict__ eidx, float* __restrict__ pval)
{
  const int wv = threadIdx.x >> 6, lane = threadIdx.x & 63;
  const int n = blockIdx.x * 4 + wv;
  const float* xr = x + (size_t)n * CDIM;
  float acc[E_EXP] = {0.f, 0.f, 0.f, 0.f, 0.f, 0.f, 0.f, 0.f};
#pragma unroll
  for (int i = 0; i < CDIM / 64; ++i) {
    const float xv = xr[i * 64 + lane];
#pragma unroll
    for (int e = 0; e < E_EXP; ++e)
      acc[e] = fmaf(xv, wg[e * CDIM + i * 64 + lane], acc[e]);
  }
#pragma unroll
  for (int e = 0; e < E_EXP; ++e) {
#pragma unroll
    for (int off = 32; off > 0; off >>= 1)
      acc[e] += __shfl_xor(acc[e], off);
  }
  if (lane == 0) {
    int e0 = 0; float v0 = acc[0];
#pragma unroll
    for (int e = 1; e < E_EXP; ++e) if (acc[e] > v0) { v0 = acc[e]; e0 = e; }
    int e1 = -1; float v1 = -3.4e38f;
#pragma unroll
    for (int e = 0; e < E_EXP; ++e) if (e != e0 && acc[e] > v1) { v1 = acc[e]; e1 = e; }
    const float ex = __expf(v1 - v0);
    const float inv = 1.f / (1.f + ex);
    eidx[n] = e0; eidx[N_TOK + n] = e1;
    pval[n] = inv; pval[N_TOK + n] = ex * inv;
  }
}

// ---------------------------------------------------------------------------
// K3: init slot_token to -1
// ---------------------------------------------------------------------------
__global__ void init_slots(int* __restrict__ p)
{
  p[blockIdx.x * 256 + threadIdx.x] = -1;
}

// ---------------------------------------------------------------------------
// K4: capacity scan (k-major reference order), single block Hillis-Steele.
// ---------------------------------------------------------------------------
__global__ __launch_bounds__(256)
void scan_kernel(const int* __restrict__ eidx, int* __restrict__ slot,
                 int* __restrict__ slot_token)
{
  const int t = threadIdx.x;
  const int base = t * 32;
  int e_local[32];
  int cnt[E_EXP] = {0, 0, 0, 0, 0, 0, 0, 0};
#pragma unroll
  for (int i = 0; i < 32; ++i) {
    const int e = eidx[base + i];
    e_local[i] = e;
    cnt[e]++;
  }
  __shared__ int hist[256][E_EXP];
#pragma unroll
  for (int e = 0; e < E_EXP; ++e) hist[t][e] = cnt[e];
  __syncthreads();
  for (int off = 1; off < 256; off <<= 1) {
    int v[E_EXP] = {0, 0, 0, 0, 0, 0, 0, 0};
    if (t >= off) {
#pragma unroll
      for (int e = 0; e < E_EXP; ++e) v[e] = hist[t - off][e];
    }
    __syncthreads();
    if (t >= off) {
#pragma unroll
      for (int e = 0; e < E_EXP; ++e) hist[t][e] += v[e];
    }
    __syncthreads();
  }
  int run[E_EXP];
#pragma unroll
  for (int e = 0; e < E_EXP; ++e) run[e] = hist[t][e] - cnt[e];
#pragma unroll
  for (int i = 0; i < 32; ++i) {
    const int a = base + i;
    const int e = e_local[i];
    const int r = run[e]++;
    const int s = (r < CAPC) ? r : -1;
    slot[a] = s;
    if (s >= 0) slot_token[e * CAPC + s] = (a < N_TOK) ? a : (a - N_TOK);
  }
}

// ---------------------------------------------------------------------------
// K5: dispatch — exp_in row = bf16(x[token]) or zeros.  One wave/slot.
// ---------------------------------------------------------------------------
__global__ __launch_bounds__(256)
void dispatch_kernel(const float* __restrict__ x, const int* __restrict__ slot_token,
                     __hip_bfloat16* __restrict__ xin)
{
  const int wv = threadIdx.x >> 6, lane = threadIdx.x & 63;
  const int s = blockIdx.x * 4 + wv;
  const int n = slot_token[s];
  unsigned short* orow = (unsigned short*)xin + (size_t)s * CDIM;
  if (n >= 0) {
    const float4* xr = (const float4*)(x + (size_t)n * CDIM);
#pragma unroll
    for (int i = 0; i < 3; ++i) {
      const float4 v = xr[i * 64 + lane];
      ushort4 o;
      o.x = f2bf(v.x); o.y = f2bf(v.y); o.z = f2bf(v.z); o.w = f2bf(v.w);
      *(ushort4*)(orow + (size_t)(i * 64 + lane) * 4) = o;
    }
  } else {
    const ushort4 z = {0, 0, 0, 0};
#pragma unroll
    for (int i = 0; i < 3; ++i)
      *(ushort4*)(orow + (size_t)(i * 64 + lane) * 4) = z;
  }
}

// ---------------------------------------------------------------------------
// K6: 256xBN-tile batched GEMM, BK=64, 8 waves (2Mx4N), per-wave 128 x BN/4.
// Compile-time K/BN/NBX -> address arithmetic strength-reduced to SGPR+imm.
// dbuf LDS (2 x (32KB A + BN*128 B)); counted vmcnt depth-2; 2 barriers/tile;
// compiler-scheduled ds_read<->MFMA interleave (no manual lgkm waits).
// vmcnt ledger (loads/thread, L=4+NI): prologue t0,t1 = 2L outstanding;
//   entry VMCNT(L) -> tile kt fully landed; stage kt+2 after mid barrier;
//   tails <L,nostage>, <0,nostage>.  XOR swizzle (row&7)<<4 both sides.
// ---------------------------------------------------------------------------
template<int BN, int Kc>
__device__ __forceinline__ void stageT(const __hip_bfloat16* __restrict__ Ae,
                                       const __hip_bfloat16* __restrict__ Be,
                                       char* dst, int kt, int wv, int lane)
{
  constexpr int NI = BN / 64;
  const int r = wv * 8 + (lane >> 3);
  const int kb = ((lane & 7) * 16) ^ ((r & 7) << 4);   // pre-swizzled source
  const char* As = (const char*)Ae + (size_t)kt * 128 + kb;
  const char* Bs = (const char*)Be + (size_t)kt * 128 + kb;
#pragma unroll
  for (int j = 0; j < 4; ++j) {
    const char* g = As + (size_t)(j * 64 + r) * (Kc * 2);
    __builtin_amdgcn_global_load_lds((const __attribute__((address_space(1))) unsigned int*)g,
                                     (__attribute__((address_space(3))) unsigned int*)(dst + j * 8192 + wv * 1024),
                                     16, 0, 0);
  }
#pragma unroll
  for (int j = 0; j < NI; ++j) {
    const char* g = Bs + (size_t)(j * 64 + r) * (Kc * 2);
    __builtin_amdgcn_global_load_lds((const __attribute__((address_space(1))) unsigned int*)g,
                                     (__attribute__((address_space(3))) unsigned int*)(dst + 32768 + j * 8192 + wv * 1024),
                                     16, 0, 0);
  }
}

template<int BN, int Kc, int VME, bool ST, int BUF>
__device__ __forceinline__ void ktileT(int kt, char* lds,
                                       const __hip_bfloat16* __restrict__ Ae,
                                       const __hip_bfloat16* __restrict__ Be,
                                       floatx4 (&acc)[8][BN / 64],
                                       int wm, int wn, int fr, int fk, int wv, int lane)
{
  constexpr int NI = BN / 64;
  constexpr int BUFS = 32768 + BN * 128;
  if constexpr (VME == 8) VMCNT(8);
  else if constexpr (VME == 7) VMCNT(7);
  else VMCNT(0);
  SB0();
  __builtin_amdgcn_s_barrier();
  SB0();
  const char* bufA = lds + BUF * BUFS;
  const char* bufB = bufA + 32768;
  short8 a[8][2], b[NI][2];
#pragma unroll
  for (int mi = 0; mi < 8; ++mi) {
    const int lr = wm * 128 + mi * 16 + fr;
#pragma unroll
    for (int kk = 0; kk < 2; ++kk)
      a[mi][kk] = *(const short8*)(bufA + lr * 128 + ((kk * 64 + fk * 16) ^ ((lr & 7) << 4)));
  }
#pragma unroll
  for (int ni = 0; ni < NI; ++ni) {
    const int lj = wn * (BN / 4) + ni * 16 + fr;
#pragma unroll
    for (int kk = 0; kk < 2; ++kk)
      b[ni][kk] = *(const short8*)(bufB + lj * 128 + ((kk * 64 + fk * 16) ^ ((lj & 7) << 4)));
  }
  __builtin_amdgcn_s_setprio(1);
#pragma unroll
  for (int kk = 0; kk < 2; ++kk)
#pragma unroll
    for (int mi = 0; mi < 8; ++mi)
#pragma unroll
      for (int ni = 0; ni < NI; ++ni)
        acc[mi][ni] = __builtin_amdgcn_mfma_f32_16x16x32_bf16(a[mi][kk], b[ni][kk], acc[mi][ni], 0, 0, 0);
  __builtin_amdgcn_s_setprio(0);
  SB0();
  __builtin_amdgcn_s_barrier();   // all waves consumed buf[BUF] (reads drained by MFMA deps)
  SB0();
  if constexpr (ST)
    stageT<BN, Kc>(Ae, Be, lds + BUF * BUFS, kt + 2, wv, lane);
  SB0();
}

template<int GELU_OUT, int BN, int Kc, int NBX>
__global__ __launch_bounds__(512, 2)
void gemmT(const __hip_bfloat16* __restrict__ A, const __hip_bfloat16* __restrict__ Bt,
           const float* __restrict__ bias, void* __restrict__ Cout)
{
  constexpr int NI  = BN / 64;
  constexpr int L   = 4 + NI;          // stage loads per thread per tile
  constexpr int Nc  = NBX * BN;
  constexpr int ntk = Kc / 64;         // even for Kc=768(12), 3072(48)
  constexpr int BUFS = 32768 + BN * 128;
  extern __shared__ __align__(16) char lds[];

  const int nwg = gridDim.x;
  int wg = blockIdx.x;
  wg = (wg & 7) * (nwg >> 3) + (wg >> 3);   // XCD chunking (nwg%8==0): 1 expert/XCD
  const int e = wg / (NBX * 8);
  const int rem = wg % (NBX * 8);
  const int by = rem / NBX, bx = rem % NBX;
  const int t = threadIdx.x, wv = t >> 6, lane = t & 63;
  const int wm = wv >> 2, wn = wv & 3;
  const int fr = lane & 15, fk = lane >> 4;

  const __hip_bfloat16* Ae = A + (size_t)e * CAPC * Kc + (size_t)by * 256 * Kc;
  const __hip_bfloat16* Be = Bt + (size_t)e * Nc * Kc + (size_t)bx * BN * Kc;

  floatx4 acc[8][NI] = {};

  stageT<BN, Kc>(Ae, Be, lds, 0, wv, lane);
  stageT<BN, Kc>(Ae, Be, lds + BUFS, 1, wv, lane);
  SB0();

#pragma unroll 1
  for (int kt = 0; kt < ntk - 2; kt += 2) {
    ktileT<BN, Kc, L, true, 0>(kt, lds, Ae, Be, acc, wm, wn, fr, fk, wv, lane);
    ktileT<BN, Kc, L, true, 1>(kt + 1, lds, Ae, Be, acc, wm, wn, fr, fk, wv, lane);
  }
  ktileT<BN, Kc, L, false, 0>(ntk - 2, lds, Ae, Be, acc, wm, wn, fr, fk, wv, lane);
  ktileT<BN, Kc, 0, false, 1>(ntk - 1, lds, Ae, Be, acc, wm, wn, fr, fk, wv, lane);

  // epilogue: C/D layout col = lane&15, row = (lane>>4)*4 + j
  const float* be = bias + (size_t)e * Nc;
  const size_t cbase = (size_t)e * CAPC * Nc;
  const int m0 = by * 256, n0 = bx * BN;

  if constexpr (GELU_OUT) {
    // LDS-staged coalesced bf16 store (wave-private 2KB region; K-loop done).
    unsigned short* ep = (unsigned short*)(lds + wv * 2048);
    unsigned short* Cb = (unsigned short*)Cout + cbase;
    float bcol[NI];
#pragma unroll
    for (int ni = 0; ni < NI; ++ni) bcol[ni] = be[n0 + wn * (BN / 4) + ni * 16 + fr];
#pragma unroll
    for (int mi = 0; mi < 8; ++mi) {
#pragma unroll
      for (int ni = 0; ni < NI; ++ni)
#pragma unroll
        for (int j = 0; j < 4; ++j) {
          float v = acc[mi][ni][j] + bcol[ni];
          v = 0.5f * v * (1.0f + erff(v * 0.70710678118654752f));
          const int row = fk * 4 + j;
          *(unsigned short*)((char*)ep + row * 128 + ((ni * 32 + fr * 2) ^ (fk << 5))) = f2bf(v);
        }
      LGKM(0); SB0();
      const int r = lane & 15;
      const int grow = m0 + wm * 128 + mi * 16 + r;
#pragma unroll
      for (int it = 0; it < 2; ++it) {
        const int q = (lane >> 4) + it * 4;
        const short8 vv = *(const short8*)((char*)ep + r * 128 + ((q * 16) ^ ((r >> 2) << 5)));
        *(short8*)(Cb + (size_t)grow * Nc + n0 + wn * 64 + q * 8) = vv;
      }
      LGKM(0); SB0();
    }
  } else {
#pragma unroll
    for (int ni = 0; ni < NI; ++ni) {
      const int col = n0 + wn * (BN / 4) + ni * 16 + fr;
      const float b = be[col];
#pragma unroll
      for (int mi = 0; mi < 8; ++mi) {
        const int rbase = m0 + wm * 128 + mi * 16 + fk * 4;
#pragma unroll
        for (int j = 0; j < 4; ++j) {
          ((float*)Cout)[cbase + (size_t)(rbase + j) * Nc + col] = acc[mi][ni][j] + b;
        }
      }
    }
  }
}

// ---------------------------------------------------------------------------
// K7: combine — out[n] = w0*exp_out[e0][s0] + w1*exp_out[e1][s1]
// ---------------------------------------------------------------------------
__global__ __launch_bounds__(256)
void combine_kernel(const float* __restrict__ eout, const int* __restrict__ eidx,
                    const float* __restrict__ pval, const int* __restrict__ slot,
                    float* __restrict__ out)
{
  const int wv = threadIdx.x >> 6, lane = threadIdx.x & 63;
  const int n = blockIdx.x * 4 + wv;
  const int e0 = eidx[n], e1 = eidx[N_TOK + n];
  int s0 = slot[n], s1 = slot[N_TOK + n];
  const float w0 = (s0 >= 0) ? pval[n] : 0.f;
  const float w1 = (s1 >= 0) ? pval[N_TOK + n] : 0.f;
  s0 = (s0 >= 0) ? s0 : 0;
  s1 = (s1 >= 0) ? s1 : 0;
  const float4* r0 = (const float4*)(eout + ((size_t)e0 * CAPC + s0) * CDIM);
  const float4* r1 = (const float4*)(eout + ((size_t)e1 * CAPC + s1) * CDIM);
  float4* o = (float4*)(out + (size_t)n * CDIM);
#pragma unroll
  for (int i = 0; i < 3; ++i) {
    const float4 a = r0[i * 64 + lane];
    const float4 b = r1[i * 64 + lane];
    float4 c;
    c.x = w0 * a.x + w1 * b.x;
    c.y = w0 * a.y + w1 * b.y;
    c.z = w0 * a.z + w1 * b.z;
    c.w = w0 * a.w + w1 * b.w;
    o[i * 64 + lane] = c;
  }
}

// ---------------------------------------------------------------------------
extern "C" void kernel_launch(void* const* d_in, const int* in_sizes, int n_in,
                              void* d_out, int out_size, void* d_ws, size_t ws_size,
                              hipStream_t stream)
{
  const float* x   = (const float*)d_in[0];
  const float* wg  = (const float*)d_in[1];
  const float* cfc = (const float*)d_in[2];
  const float* fcb = (const float*)d_in[3];
  const float* cpr = (const float*)d_in[4];
  const float* prb = (const float*)d_in[5];
  float* out = (float*)d_out;

  char* ws = (char*)d_ws;
  size_t off = 0;
  auto take = [&](size_t bytes) -> void* {
    void* p = ws + off;
    off += (bytes + 255) & ~(size_t)255;
    return p;
  };
  __hip_bfloat16* wfcT = (__hip_bfloat16*)take((size_t)E_EXP * HDIM * CDIM * 2); // [E][3072][768]
  __hip_bfloat16* wprT = (__hip_bfloat16*)take((size_t)E_EXP * CDIM * HDIM * 2); // [E][768][3072]
  __hip_bfloat16* xin  = (__hip_bfloat16*)take((size_t)E_EXP * CAPC * CDIM * 2); // [E][CAP][768]
  __hip_bfloat16* hbuf = (__hip_bfloat16*)take((size_t)E_EXP * CAPC * HDIM * 2); // [E][CAP][3072]
  float*          eout = (float*)take((size_t)E_EXP * CAPC * CDIM * 4);          // [E][CAP][768]
  int*   eidx = (int*)take((size_t)2 * N_TOK * 4);
  float* pv   = (float*)take((size_t)2 * N_TOK * 4);
  int*   slot = (int*)take((size_t)2 * N_TOK * 4);
  int*   stok = (int*)take((size_t)E_EXP * CAPC * 4);

  hipFuncSetAttribute((const void*)gemmT<1, 256, CDIM, 12>,
                      hipFuncAttributeMaxDynamicSharedMemorySize, 131072);
  hipFuncSetAttribute((const void*)gemmT<0, 192, HDIM, 4>,
                      hipFuncAttributeMaxDynamicSharedMemorySize, 114688);

  // weight transpose+convert
  transpose_convert<<<dim3(HDIM / 32, CDIM / 32, E_EXP), 256, 0, stream>>>(cfc, wfcT, CDIM, HDIM);
  transpose_convert<<<dim3(CDIM / 32, HDIM / 32, E_EXP), 256, 0, stream>>>(cpr, wprT, HDIM, CDIM);

  router_kernel<<<N_TOK / 4, 256, 0, stream>>>(x, wg, eidx, pv);
  init_slots<<<(E_EXP * CAPC) / 256, 256, 0, stream>>>(stok);
  scan_kernel<<<1, 256, 0, stream>>>(eidx, slot, stok);
  dispatch_kernel<<<(E_EXP * CAPC) / 4, 256, 0, stream>>>(x, stok, xin);

  // GEMM1 + bias + exact GELU -> h (bf16): per-expert M=2048, N=3072, K=768
  //   tile 256x256, 12x8 tiles/expert, grid 768 (96/XCD = 1 expert/XCD)
  gemmT<1, 256, CDIM, 12><<<768, 512, 131072, stream>>>(xin, wfcT, fcb, hbuf);
  // GEMM2 + bias -> exp_out (f32): per-expert M=2048, N=768, K=3072
  //   tile 256x192, 4x8 tiles/expert, grid 256 = exactly 1 block/CU
  gemmT<0, 192, HDIM, 4><<<256, 512, 114688, stream>>>(hbuf, wprT, prb, eout);

  combine_kernel<<<N_TOK / 4, 256, 0, stream>>>(eout, eidx, pv, slot, out);
}

// Round 7
// 262.401 us; speedup vs baseline: 1.5921x; 1.5921x over previous
//
#include <hip/hip_runtime.h>
#include <hip/hip_bf16.h>
#include <math.h>

// Problem constants (B=4, T=1024, C=768, E=8, K=2)
#define N_TOK 4096
#define CDIM  768
#define E_EXP 8
#define CAPC  2048
#define HDIM  3072   // 4*C

typedef __attribute__((ext_vector_type(8))) short short8;
typedef __attribute__((ext_vector_type(4))) float floatx4;

#define VMCNT(n) asm volatile("s_waitcnt vmcnt(" #n ")" ::: "memory")
#define LGKM(n)  asm volatile("s_waitcnt lgkmcnt(" #n ")" ::: "memory")
#define SB0()    __builtin_amdgcn_sched_barrier(0)

static __device__ __forceinline__ unsigned short f2bf(float f) {
  __hip_bfloat16 h = __float2bfloat16(f);
  return __builtin_bit_cast(unsigned short, h);
}

// ---------------------------------------------------------------------------
// K1: transpose + f32->bf16 convert.  in: [E][R][Cc] f32 -> out: [E][Cc][R] bf16
// ---------------------------------------------------------------------------
__global__ __launch_bounds__(256)
void transpose_convert(const float* __restrict__ in, __hip_bfloat16* __restrict__ out,
                       int R, int Cc)
{
  __shared__ float tile[32][33];
  const int e  = blockIdx.z;
  const int c0 = blockIdx.x * 32;
  const int r0 = blockIdx.y * 32;
  const float* ie = in + (size_t)e * R * Cc;
  __hip_bfloat16* oe = out + (size_t)e * Cc * R;
  const int t = threadIdx.x;
  {
    const int r = t >> 3, c = (t & 7) * 4;
    const float4 v = *(const float4*)(ie + (size_t)(r0 + r) * Cc + c0 + c);
    tile[r][c + 0] = v.x; tile[r][c + 1] = v.y; tile[r][c + 2] = v.z; tile[r][c + 3] = v.w;
  }
  __syncthreads();
  {
    const int cc = t >> 3, rr = (t & 7) * 4;
    ushort4 o;
    o.x = f2bf(tile[rr + 0][cc]);
    o.y = f2bf(tile[rr + 1][cc]);
    o.z = f2bf(tile[rr + 2][cc]);
    o.w = f2bf(tile[rr + 3][cc]);
    *(ushort4*)((unsigned short*)oe + (size_t)(c0 + cc) * R + r0 + rr) = o;
  }
}

// ---------------------------------------------------------------------------
// K2: router — logits = x @ w_g^T, top-2 + softmax over the two kept logits.
// ---------------------------------------------------------------------------
__global__ __launch_bounds__(256)
void router_kernel(const float* __restrict__ x, const float* __restrict__ wg,
                   int* __restrict__ eidx, float* __restrict__ pval)
{
  const int wv = threadIdx.x >> 6, lane = threadIdx.x & 63;
  const int n = blockIdx.x * 4 + wv;
  const float* xr = x + (size_t)n * CDIM;
  float acc[E_EXP] = {0.f, 0.f, 0.f, 0.f, 0.f, 0.f, 0.f, 0.f};
#pragma unroll
  for (int i = 0; i < CDIM / 64; ++i) {
    const float xv = xr[i * 64 + lane];
#pragma unroll
    for (int e = 0; e < E_EXP; ++e)
      acc[e] = fmaf(xv, wg[e * CDIM + i * 64 + lane], acc[e]);
  }
#pragma unroll
  for (int e = 0; e < E_EXP; ++e) {
#pragma unroll
    for (int off = 32; off > 0; off >>= 1)
      acc[e] += __shfl_xor(acc[e], off);
  }
  if (lane == 0) {
    int e0 = 0; float v0 = acc[0];
#pragma unroll
    for (int e = 1; e < E_EXP; ++e) if (acc[e] > v0) { v0 = acc[e]; e0 = e; }
    int e1 = -1; float v1 = -3.4e38f;
#pragma unroll
    for (int e = 0; e < E_EXP; ++e) if (e != e0 && acc[e] > v1) { v1 = acc[e]; e1 = e; }
    const float ex = __expf(v1 - v0);
    const float inv = 1.f / (1.f + ex);
    eidx[n] = e0; eidx[N_TOK + n] = e1;
    pval[n] = inv; pval[N_TOK + n] = ex * inv;
  }
}

// ---------------------------------------------------------------------------
// K3: init slot_token to -1
// ---------------------------------------------------------------------------
__global__ void init_slots(int* __restrict__ p)
{
  p[blockIdx.x * 256 + threadIdx.x] = -1;
}

// ---------------------------------------------------------------------------
// K4: capacity scan (k-major reference order), single block Hillis-Steele.
// ---------------------------------------------------------------------------
__global__ __launch_bounds__(256)
void scan_kernel(const int* __restrict__ eidx, int* __restrict__ slot,
                 int* __restrict__ slot_token)
{
  const int t = threadIdx.x;
  const int base = t * 32;
  int e_local[32];
  int cnt[E_EXP] = {0, 0, 0, 0, 0, 0, 0, 0};
#pragma unroll
  for (int i = 0; i < 32; ++i) {
    const int e = eidx[base + i];
    e_local[i] = e;
    cnt[e]++;
  }
  __shared__ int hist[256][E_EXP];
#pragma unroll
  for (int e = 0; e < E_EXP; ++e) hist[t][e] = cnt[e];
  __syncthreads();
  for (int off = 1; off < 256; off <<= 1) {
    int v[E_EXP] = {0, 0, 0, 0, 0, 0, 0, 0};
    if (t >= off) {
#pragma unroll
      for (int e = 0; e < E_EXP; ++e) v[e] = hist[t - off][e];
    }
    __syncthreads();
    if (t >= off) {
#pragma unroll
      for (int e = 0; e < E_EXP; ++e) hist[t][e] += v[e];
    }
    __syncthreads();
  }
  int run[E_EXP];
#pragma unroll
  for (int e = 0; e < E_EXP; ++e) run[e] = hist[t][e] - cnt[e];
#pragma unroll
  for (int i = 0; i < 32; ++i) {
    const int a = base + i;
    const int e = e_local[i];
    const int r = run[e]++;
    const int s = (r < CAPC) ? r : -1;
    slot[a] = s;
    if (s >= 0) slot_token[e * CAPC + s] = (a < N_TOK) ? a : (a - N_TOK);
  }
}

// ---------------------------------------------------------------------------
// K5: dispatch — exp_in row = bf16(x[token]) or zeros.  One wave/slot.
// ---------------------------------------------------------------------------
__global__ __launch_bounds__(256)
void dispatch_kernel(const float* __restrict__ x, const int* __restrict__ slot_token,
                     __hip_bfloat16* __restrict__ xin)
{
  const int wv = threadIdx.x >> 6, lane = threadIdx.x & 63;
  const int s = blockIdx.x * 4 + wv;
  const int n = slot_token[s];
  unsigned short* orow = (unsigned short*)xin + (size_t)s * CDIM;
  if (n >= 0) {
    const float4* xr = (const float4*)(x + (size_t)n * CDIM);
#pragma unroll
    for (int i = 0; i < 3; ++i) {
      const float4 v = xr[i * 64 + lane];
      ushort4 o;
      o.x = f2bf(v.x); o.y = f2bf(v.y); o.z = f2bf(v.z); o.w = f2bf(v.w);
      *(ushort4*)(orow + (size_t)(i * 64 + lane) * 4) = o;
    }
  } else {
    const ushort4 z = {0, 0, 0, 0};
#pragma unroll
    for (int i = 0; i < 3; ++i)
      *(ushort4*)(orow + (size_t)(i * 64 + lane) * 4) = z;
  }
}

// ---------------------------------------------------------------------------
// K6: 256xBN batched GEMM, BK=64, 8 waves (2Mx4N, per-wave 128 x BN/4).
// Compile-time Kc/BN -> strength-reduced addressing.  Register-reuse phases
// (max 64 operand VGPRs live -> no spill), single-point staging per tile,
// counted vmcnt depth-2, 2 barriers/tile, compiler-scheduled lgkmcnt.
//   p0: read A0(8)+b[0..1](4) -> MFMA A0 x b01
//   p1: read b[2..NI-1]       -> MFMA A0 x bhi     (a reused)
//   p2: read A1(8, overwrite) -> MFMA A1 x b01     (b reused)
//   barrier; stage(kt+2, L loads); p3: MFMA A1 x bhi (regs only)
// vmcnt ledger (L = 4+NI loads/thread/tile): prologue stages t0,t1 (2L);
//   entry VMCNT(L) -> tile kt fully landed; tails <L,nostage>, <0,nostage>.
// XOR swizzle (row&7)<<4 on stage-source and read (proven r1-r5).
// ---------------------------------------------------------------------------
template<int BN, int Kc>
__device__ __forceinline__ void stageT(const __hip_bfloat16* __restrict__ Ae,
                                       const __hip_bfloat16* __restrict__ Be,
                                       char* dst, int kt, int wv, int lane)
{
  constexpr int NI = BN / 64;
  const int r = wv * 8 + (lane >> 3);
  const int kb = ((lane & 7) * 16) ^ ((r & 7) << 4);   // pre-swizzled source
  const char* As = (const char*)Ae + (size_t)kt * 128 + (size_t)r * (Kc * 2) + kb;
  const char* Bs = (const char*)Be + (size_t)kt * 128 + (size_t)r * (Kc * 2) + kb;
#pragma unroll
  for (int j = 0; j < 4; ++j)
    __builtin_amdgcn_global_load_lds(
        (const __attribute__((address_space(1))) unsigned int*)(As + (size_t)j * 64 * Kc * 2),
        (__attribute__((address_space(3))) unsigned int*)(dst + j * 8192 + wv * 1024), 16, 0, 0);
#pragma unroll
  for (int j = 0; j < NI; ++j)
    __builtin_amdgcn_global_load_lds(
        (const __attribute__((address_space(1))) unsigned int*)(Bs + (size_t)j * 64 * Kc * 2),
        (__attribute__((address_space(3))) unsigned int*)(dst + 32768 + j * 8192 + wv * 1024), 16, 0, 0);
}

template<int BN, int Kc, int VME, bool ST, int BUF>
__device__ __forceinline__ void ktileT(int kt, char* lds,
                                       const __hip_bfloat16* __restrict__ Ae,
                                       const __hip_bfloat16* __restrict__ Be,
                                       floatx4 (&acc)[8][BN / 64],
                                       int wm, int wn, int fr, int fk, int wv, int lane)
{
  constexpr int NI = BN / 64;
  constexpr int BUFS = (256 + BN) * 128;
  if constexpr (VME == 8) VMCNT(8);
  else if constexpr (VME == 7) VMCNT(7);
  else VMCNT(0);
  SB0();
  __builtin_amdgcn_s_barrier();
  SB0();
  const char* bufA = lds + BUF * BUFS;
  const char* bufB = bufA + 32768;
  short8 a[4][2], b[NI][2];

  // ---- p0: read A0 + b[0..1], MFMA A0 x b01 ----
#pragma unroll
  for (int mi = 0; mi < 4; ++mi) {
    const int lr = wm * 128 + mi * 16 + fr;
#pragma unroll
    for (int kk = 0; kk < 2; ++kk)
      a[mi][kk] = *(const short8*)(bufA + lr * 128 + ((kk * 64 + fk * 16) ^ ((lr & 7) << 4)));
  }
#pragma unroll
  for (int ni = 0; ni < 2; ++ni) {
    const int lj = wn * (BN / 4) + ni * 16 + fr;
#pragma unroll
    for (int kk = 0; kk < 2; ++kk)
      b[ni][kk] = *(const short8*)(bufB + lj * 128 + ((kk * 64 + fk * 16) ^ ((lj & 7) << 4)));
  }
  __builtin_amdgcn_s_setprio(1);
#pragma unroll
  for (int kk = 0; kk < 2; ++kk)
#pragma unroll
    for (int mi = 0; mi < 4; ++mi)
#pragma unroll
      for (int ni = 0; ni < 2; ++ni)
        acc[mi][ni] = __builtin_amdgcn_mfma_f32_16x16x32_bf16(a[mi][kk], b[ni][kk], acc[mi][ni], 0, 0, 0);
  __builtin_amdgcn_s_setprio(0);
  SB0();

  // ---- p1: read b[2..NI-1], MFMA A0 x bhi ----
#pragma unroll
  for (int ni = 2; ni < NI; ++ni) {
    const int lj = wn * (BN / 4) + ni * 16 + fr;
#pragma unroll
    for (int kk = 0; kk < 2; ++kk)
      b[ni][kk] = *(const short8*)(bufB + lj * 128 + ((kk * 64 + fk * 16) ^ ((lj & 7) << 4)));
  }
  __builtin_amdgcn_s_setprio(1);
#pragma unroll
  for (int kk = 0; kk < 2; ++kk)
#pragma unroll
    for (int mi = 0; mi < 4; ++mi)
#pragma unroll
      for (int ni = 2; ni < NI; ++ni)
        acc[mi][ni] = __builtin_amdgcn_mfma_f32_16x16x32_bf16(a[mi][kk], b[ni][kk], acc[mi][ni], 0, 0, 0);
  __builtin_amdgcn_s_setprio(0);
  SB0();

  // ---- p2: read A1 (overwrite a), MFMA A1 x b01 ----
#pragma unroll
  for (int mi = 0; mi < 4; ++mi) {
    const int lr = wm * 128 + 64 + mi * 16 + fr;
#pragma unroll
    for (int kk = 0; kk < 2; ++kk)
      a[mi][kk] = *(const short8*)(bufA + lr * 128 + ((kk * 64 + fk * 16) ^ ((lr & 7) << 4)));
  }
  __builtin_amdgcn_s_setprio(1);
#pragma unroll
  for (int kk = 0; kk < 2; ++kk)
#pragma unroll
    for (int mi = 0; mi < 4; ++mi)
#pragma unroll
      for (int ni = 0; ni < 2; ++ni)
        acc[4 + mi][ni] = __builtin_amdgcn_mfma_f32_16x16x32_bf16(a[mi][kk], b[ni][kk], acc[4 + mi][ni], 0, 0, 0);
  __builtin_amdgcn_s_setprio(0);
  SB0();
  __builtin_amdgcn_s_barrier();     // all waves done reading buf[BUF]
  SB0();
  if constexpr (ST)
    stageT<BN, Kc>(Ae, Be, lds + BUF * BUFS, kt + 2, wv, lane);
  SB0();

  // ---- p3: MFMA A1 x bhi (registers only, overlaps stage issue) ----
  __builtin_amdgcn_s_setprio(1);
#pragma unroll
  for (int kk = 0; kk < 2; ++kk)
#pragma unroll
    for (int mi = 0; mi < 4; ++mi)
#pragma unroll
      for (int ni = 2; ni < NI; ++ni)
        acc[4 + mi][ni] = __builtin_amdgcn_mfma_f32_16x16x32_bf16(a[mi][kk], b[ni][kk], acc[4 + mi][ni], 0, 0, 0);
  __builtin_amdgcn_s_setprio(0);
  SB0();
}

template<int GELU_OUT, int BN, int Kc, int NBX>
__global__ __launch_bounds__(512, 2)
void gemmT(const __hip_bfloat16* __restrict__ A, const __hip_bfloat16* __restrict__ Bt,
           const float* __restrict__ bias, void* __restrict__ Cout)
{
  constexpr int NI  = BN / 64;
  constexpr int L   = 4 + NI;          // stage loads per thread per tile
  constexpr int Nc  = NBX * BN;
  constexpr int ntk = Kc / 64;         // 12 (Kc=768) / 48 (Kc=3072), even
  constexpr int BUFS = (256 + BN) * 128;
  extern __shared__ __align__(16) char lds[];

  const int nwg = gridDim.x;
  int wg = blockIdx.x;
  wg = (wg & 7) * (nwg >> 3) + (wg >> 3);   // XCD chunking (nwg%8==0): 1 expert/XCD
  const int e = wg / (NBX * 8);
  const int rem = wg % (NBX * 8);
  const int by = rem / NBX, bx = rem % NBX;
  const int t = threadIdx.x, wv = t >> 6, lane = t & 63;
  const int wm = wv >> 2, wn = wv & 3;
  const int fr = lane & 15, fk = lane >> 4;

  const __hip_bfloat16* Ae = A + (size_t)e * CAPC * Kc + (size_t)by * 256 * Kc;
  const __hip_bfloat16* Be = Bt + (size_t)e * Nc * Kc + (size_t)bx * BN * Kc;

  floatx4 acc[8][NI] = {};

  stageT<BN, Kc>(Ae, Be, lds, 0, wv, lane);
  stageT<BN, Kc>(Ae, Be, lds + BUFS, 1, wv, lane);
  SB0();

#pragma unroll 1
  for (int kt = 0; kt < ntk - 2; kt += 2) {
    ktileT<BN, Kc, L, true, 0>(kt, lds, Ae, Be, acc, wm, wn, fr, fk, wv, lane);
    ktileT<BN, Kc, L, true, 1>(kt + 1, lds, Ae, Be, acc, wm, wn, fr, fk, wv, lane);
  }
  ktileT<BN, Kc, L, false, 0>(ntk - 2, lds, Ae, Be, acc, wm, wn, fr, fk, wv, lane);
  ktileT<BN, Kc, 0, false, 1>(ntk - 1, lds, Ae, Be, acc, wm, wn, fr, fk, wv, lane);

  // epilogue: C/D layout col = lane&15, row = (lane>>4)*4 + j
  const float* be = bias + (size_t)e * Nc;
  const size_t cbase = (size_t)e * CAPC * Nc;
  const int m0 = by * 256, n0 = bx * BN;

  if constexpr (GELU_OUT) {
    // LDS-staged coalesced bf16 store (wave-private 2KB region; K-loop done).
    unsigned short* ep = (unsigned short*)(lds + wv * 2048);
    unsigned short* Cb = (unsigned short*)Cout + cbase;
    float bcol[NI];
#pragma unroll
    for (int ni = 0; ni < NI; ++ni) bcol[ni] = be[n0 + wn * (BN / 4) + ni * 16 + fr];
#pragma unroll
    for (int mi = 0; mi < 8; ++mi) {
#pragma unroll
      for (int ni = 0; ni < NI; ++ni)
#pragma unroll
        for (int j = 0; j < 4; ++j) {
          float v = acc[mi][ni][j] + bcol[ni];
          v = 0.5f * v * (1.0f + erff(v * 0.70710678118654752f));
          const int row = fk * 4 + j;
          *(unsigned short*)((char*)ep + row * 128 + ((ni * 32 + fr * 2) ^ (fk << 5))) = f2bf(v);
        }
      LGKM(0); SB0();
      const int r = lane & 15;
      const int grow = m0 + wm * 128 + mi * 16 + r;
#pragma unroll
      for (int it = 0; it < 2; ++it) {
        const int q = (lane >> 4) + it * 4;
        const short8 vv = *(const short8*)((char*)ep + r * 128 + ((q * 16) ^ ((r >> 2) << 5)));
        *(short8*)(Cb + (size_t)grow * Nc + n0 + wn * 64 + q * 8) = vv;
      }
      LGKM(0); SB0();
    }
  } else {
#pragma unroll
    for (int ni = 0; ni < NI; ++ni) {
      const int col = n0 + wn * (BN / 4) + ni * 16 + fr;
      const float b = be[col];
#pragma unroll
      for (int mi = 0; mi < 8; ++mi) {
        const int rbase = m0 + wm * 128 + mi * 16 + fk * 4;
#pragma unroll
        for (int j = 0; j < 4; ++j) {
          ((float*)Cout)[cbase + (size_t)(rbase + j) * Nc + col] = acc[mi][ni][j] + b;
        }
      }
    }
  }
}

// ---------------------------------------------------------------------------
// K7: combine — out[n] = w0*exp_out[e0][s0] + w1*exp_out[e1][s1]
// ---------------------------------------------------------------------------
__global__ __launch_bounds__(256)
void combine_kernel(const float* __restrict__ eout, const int* __restrict__ eidx,
                    const float* __restrict__ pval, const int* __restrict__ slot,
                    float* __restrict__ out)
{
  const int wv = threadIdx.x >> 6, lane = threadIdx.x & 63;
  const int n = blockIdx.x * 4 + wv;
  const int e0 = eidx[n], e1 = eidx[N_TOK + n];
  int s0 = slot[n], s1 = slot[N_TOK + n];
  const float w0 = (s0 >= 0) ? pval[n] : 0.f;
  const float w1 = (s1 >= 0) ? pval[N_TOK + n] : 0.f;
  s0 = (s0 >= 0) ? s0 : 0;
  s1 = (s1 >= 0) ? s1 : 0;
  const float4* r0 = (const float4*)(eout + ((size_t)e0 * CAPC + s0) * CDIM);
  const float4* r1 = (const float4*)(eout + ((size_t)e1 * CAPC + s1) * CDIM);
  float4* o = (float4*)(out + (size_t)n * CDIM);
#pragma unroll
  for (int i = 0; i < 3; ++i) {
    const float4 a = r0[i * 64 + lane];
    const float4 b = r1[i * 64 + lane];
    float4 c;
    c.x = w0 * a.x + w1 * b.x;
    c.y = w0 * a.y + w1 * b.y;
    c.z = w0 * a.z + w1 * b.z;
    c.w = w0 * a.w + w1 * b.w;
    o[i * 64 + lane] = c;
  }
}

// ---------------------------------------------------------------------------
extern "C" void kernel_launch(void* const* d_in, const int* in_sizes, int n_in,
                              void* d_out, int out_size, void* d_ws, size_t ws_size,
                              hipStream_t stream)
{
  const float* x   = (const float*)d_in[0];
  const float* wg  = (const float*)d_in[1];
  const float* cfc = (const float*)d_in[2];
  const float* fcb = (const float*)d_in[3];
  const float* cpr = (const float*)d_in[4];
  const float* prb = (const float*)d_in[5];
  float* out = (float*)d_out;

  char* ws = (char*)d_ws;
  size_t off = 0;
  auto take = [&](size_t bytes) -> void* {
    void* p = ws + off;
    off += (bytes + 255) & ~(size_t)255;
    return p;
  };
  __hip_bfloat16* wfcT = (__hip_bfloat16*)take((size_t)E_EXP * HDIM * CDIM * 2); // [E][3072][768]
  __hip_bfloat16* wprT = (__hip_bfloat16*)take((size_t)E_EXP * CDIM * HDIM * 2); // [E][768][3072]
  __hip_bfloat16* xin  = (__hip_bfloat16*)take((size_t)E_EXP * CAPC * CDIM * 2); // [E][CAP][768]
  __hip_bfloat16* hbuf = (__hip_bfloat16*)take((size_t)E_EXP * CAPC * HDIM * 2); // [E][CAP][3072]
  float*          eout = (float*)take((size_t)E_EXP * CAPC * CDIM * 4);          // [E][CAP][768]
  int*   eidx = (int*)take((size_t)2 * N_TOK * 4);
  float* pv   = (float*)take((size_t)2 * N_TOK * 4);
  int*   slot = (int*)take((size_t)2 * N_TOK * 4);
  int*   stok = (int*)take((size_t)E_EXP * CAPC * 4);

  hipFuncSetAttribute((const void*)gemmT<1, 256, CDIM, 12>,
                      hipFuncAttributeMaxDynamicSharedMemorySize, 131072);
  hipFuncSetAttribute((const void*)gemmT<0, 192, HDIM, 4>,
                      hipFuncAttributeMaxDynamicSharedMemorySize, 114688);

  // weight transpose+convert
  transpose_convert<<<dim3(HDIM / 32, CDIM / 32, E_EXP), 256, 0, stream>>>(cfc, wfcT, CDIM, HDIM);
  transpose_convert<<<dim3(CDIM / 32, HDIM / 32, E_EXP), 256, 0, stream>>>(cpr, wprT, HDIM, CDIM);

  router_kernel<<<N_TOK / 4, 256, 0, stream>>>(x, wg, eidx, pv);
  init_slots<<<(E_EXP * CAPC) / 256, 256, 0, stream>>>(stok);
  scan_kernel<<<1, 256, 0, stream>>>(eidx, slot, stok);
  dispatch_kernel<<<(E_EXP * CAPC) / 4, 256, 0, stream>>>(x, stok, xin);

  // GEMM1 + bias + exact GELU -> h (bf16): per-expert M=2048, N=3072, K=768
  //   tile 256x256, 12x8 tiles/expert, grid 768 (96/XCD = 1 expert/XCD)
  gemmT<1, 256, CDIM, 12><<<768, 512, 131072, stream>>>(xin, wfcT, fcb, hbuf);
  // GEMM2 + bias -> exp_out (f32): per-expert M=2048, N=768, K=3072
  //   tile 256x192, 4x8 tiles/expert, grid 256 = exactly 1 block/CU, one round
  gemmT<0, 192, HDIM, 4><<<256, 512, 114688, stream>>>(hbuf, wprT, prb, eout);

  combine_kernel<<<N_TOK / 4, 256, 0, stream>>>(eout, eidx, pv, slot, out);
}

// Round 8
// 204.507 us; speedup vs baseline: 2.0429x; 1.2831x over previous
//
#include <hip/hip_runtime.h>
#include <hip/hip_bf16.h>
#include <math.h>

// Problem constants (B=4, T=1024, C=768, E=8, K=2)
#define N_TOK 4096
#define CDIM  768
#define E_EXP 8
#define CAPC  2048
#define HDIM  3072   // 4*C

typedef __attribute__((ext_vector_type(8))) short short8;
typedef __attribute__((ext_vector_type(4))) float floatx4;

#define VMCNT(n) asm volatile("s_waitcnt vmcnt(" #n ")" ::: "memory")
#define LGKM(n)  asm volatile("s_waitcnt lgkmcnt(" #n ")" ::: "memory")
#define SB0()    __builtin_amdgcn_sched_barrier(0)

static __device__ __forceinline__ unsigned short f2bf(float f) {
  __hip_bfloat16 h = __float2bfloat16(f);
  return __builtin_bit_cast(unsigned short, h);
}

// ---------------------------------------------------------------------------
// K1: transpose + f32->bf16 convert.  in: [E][R][Cc] f32 -> out: [E][Cc][R] bf16
// ---------------------------------------------------------------------------
__global__ __launch_bounds__(256)
void transpose_convert(const float* __restrict__ in, __hip_bfloat16* __restrict__ out,
                       int R, int Cc)
{
  __shared__ float tile[32][33];
  const int e  = blockIdx.z;
  const int c0 = blockIdx.x * 32;
  const int r0 = blockIdx.y * 32;
  const float* ie = in + (size_t)e * R * Cc;
  __hip_bfloat16* oe = out + (size_t)e * Cc * R;
  const int t = threadIdx.x;
  {
    const int r = t >> 3, c = (t & 7) * 4;
    const float4 v = *(const float4*)(ie + (size_t)(r0 + r) * Cc + c0 + c);
    tile[r][c + 0] = v.x; tile[r][c + 1] = v.y; tile[r][c + 2] = v.z; tile[r][c + 3] = v.w;
  }
  __syncthreads();
  {
    const int cc = t >> 3, rr = (t & 7) * 4;
    ushort4 o;
    o.x = f2bf(tile[rr + 0][cc]);
    o.y = f2bf(tile[rr + 1][cc]);
    o.z = f2bf(tile[rr + 2][cc]);
    o.w = f2bf(tile[rr + 3][cc]);
    *(ushort4*)((unsigned short*)oe + (size_t)(c0 + cc) * R + r0 + rr) = o;
  }
}

// ---------------------------------------------------------------------------
// K2: router — logits = x @ w_g^T, top-2 + softmax over the two kept logits.
// ---------------------------------------------------------------------------
__global__ __launch_bounds__(256)
void router_kernel(const float* __restrict__ x, const float* __restrict__ wg,
                   int* __restrict__ eidx, float* __restrict__ pval)
{
  const int wv = threadIdx.x >> 6, lane = threadIdx.x & 63;
  const int n = blockIdx.x * 4 + wv;
  const float* xr = x + (size_t)n * CDIM;
  float acc[E_EXP] = {0.f, 0.f, 0.f, 0.f, 0.f, 0.f, 0.f, 0.f};
#pragma unroll
  for (int i = 0; i < CDIM / 64; ++i) {
    const float xv = xr[i * 64 + lane];
#pragma unroll
    for (int e = 0; e < E_EXP; ++e)
      acc[e] = fmaf(xv, wg[e * CDIM + i * 64 + lane], acc[e]);
  }
#pragma unroll
  for (int e = 0; e < E_EXP; ++e) {
#pragma unroll
    for (int off = 32; off > 0; off >>= 1)
      acc[e] += __shfl_xor(acc[e], off);
  }
  if (lane == 0) {
    int e0 = 0; float v0 = acc[0];
#pragma unroll
    for (int e = 1; e < E_EXP; ++e) if (acc[e] > v0) { v0 = acc[e]; e0 = e; }
    int e1 = -1; float v1 = -3.4e38f;
#pragma unroll
    for (int e = 0; e < E_EXP; ++e) if (e != e0 && acc[e] > v1) { v1 = acc[e]; e1 = e; }
    const float ex = __expf(v1 - v0);
    const float inv = 1.f / (1.f + ex);
    eidx[n] = e0; eidx[N_TOK + n] = e1;
    pval[n] = inv; pval[N_TOK + n] = ex * inv;
  }
}

// ---------------------------------------------------------------------------
// K3: init slot_token to -1
// ---------------------------------------------------------------------------
__global__ void init_slots(int* __restrict__ p)
{
  p[blockIdx.x * 256 + threadIdx.x] = -1;
}

// ---------------------------------------------------------------------------
// K4: capacity scan (k-major reference order), single block Hillis-Steele.
// Also emits ecnt[e] = min(total assignments to e, CAP) = used queue length.
// ---------------------------------------------------------------------------
__global__ __launch_bounds__(256)
void scan_kernel(const int* __restrict__ eidx, int* __restrict__ slot,
                 int* __restrict__ slot_token, int* __restrict__ ecnt)
{
  const int t = threadIdx.x;
  const int base = t * 32;
  int e_local[32];
  int cnt[E_EXP] = {0, 0, 0, 0, 0, 0, 0, 0};
#pragma unroll
  for (int i = 0; i < 32; ++i) {
    const int e = eidx[base + i];
    e_local[i] = e;
    cnt[e]++;
  }
  __shared__ int hist[256][E_EXP];
#pragma unroll
  for (int e = 0; e < E_EXP; ++e) hist[t][e] = cnt[e];
  __syncthreads();
  for (int off = 1; off < 256; off <<= 1) {
    int v[E_EXP] = {0, 0, 0, 0, 0, 0, 0, 0};
    if (t >= off) {
#pragma unroll
      for (int e = 0; e < E_EXP; ++e) v[e] = hist[t - off][e];
    }
    __syncthreads();
    if (t >= off) {
#pragma unroll
      for (int e = 0; e < E_EXP; ++e) hist[t][e] += v[e];
    }
    __syncthreads();
  }
  if (t == 255) {
#pragma unroll
    for (int e = 0; e < E_EXP; ++e) {
      const int tot = hist[255][e];
      ecnt[e] = tot < CAPC ? tot : CAPC;
    }
  }
  int run[E_EXP];
#pragma unroll
  for (int e = 0; e < E_EXP; ++e) run[e] = hist[t][e] - cnt[e];
#pragma unroll
  for (int i = 0; i < 32; ++i) {
    const int a = base + i;
    const int e = e_local[i];
    const int r = run[e]++;
    const int s = (r < CAPC) ? r : -1;
    slot[a] = s;
    if (s >= 0) slot_token[e * CAPC + s] = (a < N_TOK) ? a : (a - N_TOK);
  }
}

// ---------------------------------------------------------------------------
// K5: dispatch — exp_in row = bf16(x[token]); unused slots left untouched
// (their expert outputs are never read by combine: rank < count always).
// ---------------------------------------------------------------------------
__global__ __launch_bounds__(256)
void dispatch_kernel(const float* __restrict__ x, const int* __restrict__ slot_token,
                     __hip_bfloat16* __restrict__ xin)
{
  const int wv = threadIdx.x >> 6, lane = threadIdx.x & 63;
  const int s = blockIdx.x * 4 + wv;
  const int n = slot_token[s];
  if (n < 0) return;
  unsigned short* orow = (unsigned short*)xin + (size_t)s * CDIM;
  const float4* xr = (const float4*)(x + (size_t)n * CDIM);
#pragma unroll
  for (int i = 0; i < 3; ++i) {
    const float4 v = xr[i * 64 + lane];
    ushort4 o;
    o.x = f2bf(v.x); o.y = f2bf(v.y); o.z = f2bf(v.z); o.w = f2bf(v.w);
    *(ushort4*)(orow + (size_t)(i * 64 + lane) * 4) = o;
  }
}

// ---------------------------------------------------------------------------
// K6a: GEMM1 — 256x256 tile, BK=64, 8 waves (2Mx4N), compile-time addressing,
// register-reuse phases, counted vmcnt depth-2, 2 barriers/tile (round-7 body)
// + EARLY EXIT for m-tiles beyond the expert's used queue length.
// ---------------------------------------------------------------------------
template<int BN, int Kc>
__device__ __forceinline__ void stageT(const __hip_bfloat16* __restrict__ Ae,
                                       const __hip_bfloat16* __restrict__ Be,
                                       char* dst, int kt, int wv, int lane)
{
  constexpr int NI = BN / 64;
  const int r = wv * 8 + (lane >> 3);
  const int kb = ((lane & 7) * 16) ^ ((r & 7) << 4);   // pre-swizzled source
  const char* As = (const char*)Ae + (size_t)kt * 128 + (size_t)r * (Kc * 2) + kb;
  const char* Bs = (const char*)Be + (size_t)kt * 128 + (size_t)r * (Kc * 2) + kb;
#pragma unroll
  for (int j = 0; j < 4; ++j)
    __builtin_amdgcn_global_load_lds(
        (const __attribute__((address_space(1))) unsigned int*)(As + (size_t)j * 64 * Kc * 2),
        (__attribute__((address_space(3))) unsigned int*)(dst + j * 8192 + wv * 1024), 16, 0, 0);
#pragma unroll
  for (int j = 0; j < NI; ++j)
    __builtin_amdgcn_global_load_lds(
        (const __attribute__((address_space(1))) unsigned int*)(Bs + (size_t)j * 64 * Kc * 2),
        (__attribute__((address_space(3))) unsigned int*)(dst + 32768 + j * 8192 + wv * 1024), 16, 0, 0);
}

template<int BN, int Kc, int VME, bool ST, int BUF>
__device__ __forceinline__ void ktileT(int kt, char* lds,
                                       const __hip_bfloat16* __restrict__ Ae,
                                       const __hip_bfloat16* __restrict__ Be,
                                       floatx4 (&acc)[8][BN / 64],
                                       int wm, int wn, int fr, int fk, int wv, int lane)
{
  constexpr int NI = BN / 64;
  constexpr int BUFS = (256 + BN) * 128;
  if constexpr (VME == 8) VMCNT(8);
  else if constexpr (VME == 7) VMCNT(7);
  else VMCNT(0);
  SB0();
  __builtin_amdgcn_s_barrier();
  SB0();
  const char* bufA = lds + BUF * BUFS;
  const char* bufB = bufA + 32768;
  short8 a[4][2], b[NI][2];

  // ---- p0: read A0 + b[0..1], MFMA A0 x b01 ----
#pragma unroll
  for (int mi = 0; mi < 4; ++mi) {
    const int lr = wm * 128 + mi * 16 + fr;
#pragma unroll
    for (int kk = 0; kk < 2; ++kk)
      a[mi][kk] = *(const short8*)(bufA + lr * 128 + ((kk * 64 + fk * 16) ^ ((lr & 7) << 4)));
  }
#pragma unroll
  for (int ni = 0; ni < 2; ++ni) {
    const int lj = wn * (BN / 4) + ni * 16 + fr;
#pragma unroll
    for (int kk = 0; kk < 2; ++kk)
      b[ni][kk] = *(const short8*)(bufB + lj * 128 + ((kk * 64 + fk * 16) ^ ((lj & 7) << 4)));
  }
  __builtin_amdgcn_s_setprio(1);
#pragma unroll
  for (int kk = 0; kk < 2; ++kk)
#pragma unroll
    for (int mi = 0; mi < 4; ++mi)
#pragma unroll
      for (int ni = 0; ni < 2; ++ni)
        acc[mi][ni] = __builtin_amdgcn_mfma_f32_16x16x32_bf16(a[mi][kk], b[ni][kk], acc[mi][ni], 0, 0, 0);
  __builtin_amdgcn_s_setprio(0);
  SB0();

  // ---- p1: read b[2..NI-1], MFMA A0 x bhi ----
#pragma unroll
  for (int ni = 2; ni < NI; ++ni) {
    const int lj = wn * (BN / 4) + ni * 16 + fr;
#pragma unroll
    for (int kk = 0; kk < 2; ++kk)
      b[ni][kk] = *(const short8*)(bufB + lj * 128 + ((kk * 64 + fk * 16) ^ ((lj & 7) << 4)));
  }
  __builtin_amdgcn_s_setprio(1);
#pragma unroll
  for (int kk = 0; kk < 2; ++kk)
#pragma unroll
    for (int mi = 0; mi < 4; ++mi)
#pragma unroll
      for (int ni = 2; ni < NI; ++ni)
        acc[mi][ni] = __builtin_amdgcn_mfma_f32_16x16x32_bf16(a[mi][kk], b[ni][kk], acc[mi][ni], 0, 0, 0);
  __builtin_amdgcn_s_setprio(0);
  SB0();

  // ---- p2: read A1 (overwrite a), MFMA A1 x b01 ----
#pragma unroll
  for (int mi = 0; mi < 4; ++mi) {
    const int lr = wm * 128 + 64 + mi * 16 + fr;
#pragma unroll
    for (int kk = 0; kk < 2; ++kk)
      a[mi][kk] = *(const short8*)(bufA + lr * 128 + ((kk * 64 + fk * 16) ^ ((lr & 7) << 4)));
  }
  __builtin_amdgcn_s_setprio(1);
#pragma unroll
  for (int kk = 0; kk < 2; ++kk)
#pragma unroll
    for (int mi = 0; mi < 4; ++mi)
#pragma unroll
      for (int ni = 0; ni < 2; ++ni)
        acc[4 + mi][ni] = __builtin_amdgcn_mfma_f32_16x16x32_bf16(a[mi][kk], b[ni][kk], acc[4 + mi][ni], 0, 0, 0);
  __builtin_amdgcn_s_setprio(0);
  SB0();
  __builtin_amdgcn_s_barrier();     // all waves done reading buf[BUF]
  SB0();
  if constexpr (ST)
    stageT<BN, Kc>(Ae, Be, lds + BUF * BUFS, kt + 2, wv, lane);
  SB0();

  // ---- p3: MFMA A1 x bhi (registers only, overlaps stage issue) ----
  __builtin_amdgcn_s_setprio(1);
#pragma unroll
  for (int kk = 0; kk < 2; ++kk)
#pragma unroll
    for (int mi = 0; mi < 4; ++mi)
#pragma unroll
      for (int ni = 2; ni < NI; ++ni)
        acc[4 + mi][ni] = __builtin_amdgcn_mfma_f32_16x16x32_bf16(a[mi][kk], b[ni][kk], acc[4 + mi][ni], 0, 0, 0);
  __builtin_amdgcn_s_setprio(0);
  SB0();
}

template<int GELU_OUT, int BN, int Kc, int NBX>
__global__ __launch_bounds__(512, 2)
void gemmT(const __hip_bfloat16* __restrict__ A, const __hip_bfloat16* __restrict__ Bt,
           const float* __restrict__ bias, void* __restrict__ Cout,
           const int* __restrict__ ecnt)
{
  constexpr int NI  = BN / 64;
  constexpr int L   = 4 + NI;
  constexpr int Nc  = NBX * BN;
  constexpr int ntk = Kc / 64;
  constexpr int BUFS = (256 + BN) * 128;
  extern __shared__ __align__(16) char lds[];

  const int nwg = gridDim.x;
  int wg = blockIdx.x;
  wg = (wg & 7) * (nwg >> 3) + (wg >> 3);   // XCD chunking (nwg%8==0): 1 expert/XCD
  const int e = wg / (NBX * 8);
  const int rem = wg % (NBX * 8);
  const int by = rem / NBX, bx = rem % NBX;
  if (by * 256 >= ecnt[e]) return;          // skip m-tiles past used queue length
  const int t = threadIdx.x, wv = t >> 6, lane = t & 63;
  const int wm = wv >> 2, wn = wv & 3;
  const int fr = lane & 15, fk = lane >> 4;

  const __hip_bfloat16* Ae = A + (size_t)e * CAPC * Kc + (size_t)by * 256 * Kc;
  const __hip_bfloat16* Be = Bt + (size_t)e * Nc * Kc + (size_t)bx * BN * Kc;

  floatx4 acc[8][NI] = {};

  stageT<BN, Kc>(Ae, Be, lds, 0, wv, lane);
  stageT<BN, Kc>(Ae, Be, lds + BUFS, 1, wv, lane);
  SB0();

#pragma unroll 1
  for (int kt = 0; kt < ntk - 2; kt += 2) {
    ktileT<BN, Kc, L, true, 0>(kt, lds, Ae, Be, acc, wm, wn, fr, fk, wv, lane);
    ktileT<BN, Kc, L, true, 1>(kt + 1, lds, Ae, Be, acc, wm, wn, fr, fk, wv, lane);
  }
  ktileT<BN, Kc, L, false, 0>(ntk - 2, lds, Ae, Be, acc, wm, wn, fr, fk, wv, lane);
  ktileT<BN, Kc, 0, false, 1>(ntk - 1, lds, Ae, Be, acc, wm, wn, fr, fk, wv, lane);

  const float* be = bias + (size_t)e * Nc;
  const size_t cbase = (size_t)e * CAPC * Nc;
  const int m0 = by * 256, n0 = bx * BN;

  if constexpr (GELU_OUT) {
    unsigned short* ep = (unsigned short*)(lds + wv * 2048);
    unsigned short* Cb = (unsigned short*)Cout + cbase;
    float bcol[NI];
#pragma unroll
    for (int ni = 0; ni < NI; ++ni) bcol[ni] = be[n0 + wn * (BN / 4) + ni * 16 + fr];
#pragma unroll
    for (int mi = 0; mi < 8; ++mi) {
#pragma unroll
      for (int ni = 0; ni < NI; ++ni)
#pragma unroll
        for (int j = 0; j < 4; ++j) {
          float v = acc[mi][ni][j] + bcol[ni];
          v = 0.5f * v * (1.0f + erff(v * 0.70710678118654752f));
          const int row = fk * 4 + j;
          *(unsigned short*)((char*)ep + row * 128 + ((ni * 32 + fr * 2) ^ (fk << 5))) = f2bf(v);
        }
      LGKM(0); SB0();
      const int r = lane & 15;
      const int grow = m0 + wm * 128 + mi * 16 + r;
#pragma unroll
      for (int it = 0; it < 2; ++it) {
        const int q = (lane >> 4) + it * 4;
        const short8 vv = *(const short8*)((char*)ep + r * 128 + ((q * 16) ^ ((r >> 2) << 5)));
        *(short8*)(Cb + (size_t)grow * Nc + n0 + wn * 64 + q * 8) = vv;
      }
      LGKM(0); SB0();
    }
  } else {
#pragma unroll
    for (int ni = 0; ni < NI; ++ni) {
      const int col = n0 + wn * (BN / 4) + ni * 16 + fr;
      const float b = be[col];
#pragma unroll
      for (int mi = 0; mi < 8; ++mi) {
        const int rbase = m0 + wm * 128 + mi * 16 + fk * 4;
#pragma unroll
        for (int j = 0; j < 4; ++j) {
          ((float*)Cout)[cbase + (size_t)(rbase + j) * Nc + col] = acc[mi][ni][j] + b;
        }
      }
    }
  }
}

// ---------------------------------------------------------------------------
// K6b: GEMM2 — 128x128 tile, BK=64, 4 waves (2Mx2N, 64x64/wave), dbuf 64 KiB
// -> 2-3 blocks/CU so early-exited blocks free capacity that refills with
// real work (round-5 body, proven correct) + EARLY EXIT per ecnt.
// ---------------------------------------------------------------------------
__device__ __forceinline__ void stage_ab(const __hip_bfloat16* Ae, const __hip_bfloat16* Be,
                                         char* lds, int K, int kt, int isB,
                                         int wv, int lane)
{
  const char* src = (const char*)(isB ? Be : Ae);
  char* dst = lds + (kt & 1) * 32768 + isB * 16384;
#pragma unroll
  for (int j = 0; j < 4; ++j) {
    const int li = j * 32 + wv * 8 + (lane >> 3);
    const int kb = ((lane & 7) * 16) ^ ((li & 7) << 4);  // pre-swizzled source
    const char* g = src + ((size_t)li * K + (size_t)kt * 64) * 2 + kb;
    char* lp = dst + j * 4096 + wv * 1024;
    __builtin_amdgcn_global_load_lds((const __attribute__((address_space(1))) unsigned int*)g,
                                     (__attribute__((address_space(3))) unsigned int*)lp, 16, 0, 0);
  }
}

template<int VME, bool S2>
__device__ __forceinline__ void ktile2(int kt, char* lds,
                                       const __hip_bfloat16* Ae, const __hip_bfloat16* Be,
                                       int K, floatx4 (&acc)[4][4],
                                       int wm, int wn, int fr, int fk, int wv, int lane)
{
  if constexpr (VME == 8) VMCNT(8); else VMCNT(0);
  __builtin_amdgcn_s_barrier();
  SB0();
  const char* bufA = lds + ((kt & 1) ? 32768 : 0);
  const char* bufB = bufA + 16384;
  short8 a[4][2], b[4][2];
#pragma unroll
  for (int mi = 0; mi < 4; ++mi) {
    const int lr = wm * 64 + mi * 16 + fr;
    a[mi][0] = *(const short8*)(bufA + lr * 128 + ((fk * 16) ^ ((lr & 7) << 4)));
  }
#pragma unroll
  for (int ni = 0; ni < 4; ++ni) {
    const int lj = wn * 64 + ni * 16 + fr;
    b[ni][0] = *(const short8*)(bufB + lj * 128 + ((fk * 16) ^ ((lj & 7) << 4)));
  }
  SB0();
#pragma unroll
  for (int mi = 0; mi < 4; ++mi) {
    const int lr = wm * 64 + mi * 16 + fr;
    a[mi][1] = *(const short8*)(bufA + lr * 128 + ((64 + fk * 16) ^ ((lr & 7) << 4)));
  }
#pragma unroll
  for (int ni = 0; ni < 4; ++ni) {
    const int lj = wn * 64 + ni * 16 + fr;
    b[ni][1] = *(const short8*)(bufB + lj * 128 + ((64 + fk * 16) ^ ((lj & 7) << 4)));
  }
  SB0();
  LGKM(8); SB0();
  __builtin_amdgcn_s_setprio(1);
#pragma unroll
  for (int mi = 0; mi < 4; ++mi)
#pragma unroll
    for (int ni = 0; ni < 4; ++ni)
      acc[mi][ni] = __builtin_amdgcn_mfma_f32_16x16x32_bf16(a[mi][0], b[ni][0], acc[mi][ni], 0, 0, 0);
  __builtin_amdgcn_s_setprio(0);
  SB0();
  LGKM(0); SB0();
  __builtin_amdgcn_s_setprio(1);
#pragma unroll
  for (int mi = 0; mi < 4; ++mi)
#pragma unroll
    for (int ni = 0; ni < 4; ++ni)
      acc[mi][ni] = __builtin_amdgcn_mfma_f32_16x16x32_bf16(a[mi][1], b[ni][1], acc[mi][ni], 0, 0, 0);
  __builtin_amdgcn_s_setprio(0);
  SB0();
  __builtin_amdgcn_s_barrier();
  if (S2) {
    stage_ab(Ae, Be, lds, K, kt + 2, 0, wv, lane);
    stage_ab(Ae, Be, lds, K, kt + 2, 1, wv, lane);
  }
  SB0();
}

__global__ __launch_bounds__(256, 2)
void gemm2b(const __hip_bfloat16* __restrict__ A, const __hip_bfloat16* __restrict__ Bt,
            const float* __restrict__ bias, float* __restrict__ Cout,
            int M, int Nn, int K, int nbx, int nby, const int* __restrict__ ecnt)
{
  extern __shared__ __align__(16) char lds[];
  const int nwg = gridDim.x;
  int wg = blockIdx.x;
  wg = (wg & 7) * (nwg >> 3) + (wg >> 3);       // bijective XCD chunking (nwg%8==0)
  const int e = wg / (nbx * nby);
  const int rem = wg % (nbx * nby);
  const int by = rem / nbx, bx = rem % nbx;
  if (by * 128 >= ecnt[e]) return;              // skip m-tiles past used queue length
  const int t = threadIdx.x, wv = t >> 6, lane = t & 63;
  const int wm = wv >> 1, wn = wv & 1;
  const int fr = lane & 15, fk = lane >> 4;
  const int ntk = K >> 6;

  const __hip_bfloat16* Ae = A + (size_t)e * M * K + (size_t)by * 128 * K;
  const __hip_bfloat16* Be = Bt + (size_t)e * Nn * K + (size_t)bx * 128 * K;

  floatx4 acc[4][4] = {};

  stage_ab(Ae, Be, lds, K, 0, 0, wv, lane);
  stage_ab(Ae, Be, lds, K, 0, 1, wv, lane);
  stage_ab(Ae, Be, lds, K, 1, 0, wv, lane);
  stage_ab(Ae, Be, lds, K, 1, 1, wv, lane);
  SB0();

  for (int kt = 0; kt < ntk - 2; ++kt)
    ktile2<8, true>(kt, lds, Ae, Be, K, acc, wm, wn, fr, fk, wv, lane);
  ktile2<8, false>(ntk - 2, lds, Ae, Be, K, acc, wm, wn, fr, fk, wv, lane);
  ktile2<0, false>(ntk - 1, lds, Ae, Be, K, acc, wm, wn, fr, fk, wv, lane);

  const float* be = bias + (size_t)e * Nn;
  const size_t cbase = (size_t)e * M * Nn;
  const int m0 = by * 128, n0 = bx * 128;
#pragma unroll
  for (int ni = 0; ni < 4; ++ni) {
    const int col = n0 + wn * 64 + ni * 16 + fr;
    const float b = be[col];
#pragma unroll
    for (int mi = 0; mi < 4; ++mi) {
      const int rbase = m0 + wm * 64 + mi * 16 + fk * 4;
#pragma unroll
      for (int j = 0; j < 4; ++j) {
        Cout[cbase + (size_t)(rbase + j) * Nn + col] = acc[mi][ni][j] + b;
      }
    }
  }
}

// ---------------------------------------------------------------------------
// K7: combine — out[n] = w0*exp_out[e0][s0] + w1*exp_out[e1][s1]
// ---------------------------------------------------------------------------
__global__ __launch_bounds__(256)
void combine_kernel(const float* __restrict__ eout, const int* __restrict__ eidx,
                    const float* __restrict__ pval, const int* __restrict__ slot,
                    float* __restrict__ out)
{
  const int wv = threadIdx.x >> 6, lane = threadIdx.x & 63;
  const int n = blockIdx.x * 4 + wv;
  const int e0 = eidx[n], e1 = eidx[N_TOK + n];
  int s0 = slot[n], s1 = slot[N_TOK + n];
  const float w0 = (s0 >= 0) ? pval[n] : 0.f;
  const float w1 = (s1 >= 0) ? pval[N_TOK + n] : 0.f;
  s0 = (s0 >= 0) ? s0 : 0;
  s1 = (s1 >= 0) ? s1 : 0;
  const float4* r0 = (const float4*)(eout + ((size_t)e0 * CAPC + s0) * CDIM);
  const float4* r1 = (const float4*)(eout + ((size_t)e1 * CAPC + s1) * CDIM);
  float4* o = (float4*)(out + (size_t)n * CDIM);
#pragma unroll
  for (int i = 0; i < 3; ++i) {
    const float4 a = r0[i * 64 + lane];
    const float4 b = r1[i * 64 + lane];
    float4 c;
    c.x = w0 * a.x + w1 * b.x;
    c.y = w0 * a.y + w1 * b.y;
    c.z = w0 * a.z + w1 * b.z;
    c.w = w0 * a.w + w1 * b.w;
    o[i * 64 + lane] = c;
  }
}

// ---------------------------------------------------------------------------
extern "C" void kernel_launch(void* const* d_in, const int* in_sizes, int n_in,
                              void* d_out, int out_size, void* d_ws, size_t ws_size,
                              hipStream_t stream)
{
  const float* x   = (const float*)d_in[0];
  const float* wg  = (const float*)d_in[1];
  const float* cfc = (const float*)d_in[2];
  const float* fcb = (const float*)d_in[3];
  const float* cpr = (const float*)d_in[4];
  const float* prb = (const float*)d_in[5];
  float* out = (float*)d_out;

  char* ws = (char*)d_ws;
  size_t off = 0;
  auto take = [&](size_t bytes) -> void* {
    void* p = ws + off;
    off += (bytes + 255) & ~(size_t)255;
    return p;
  };
  __hip_bfloat16* wfcT = (__hip_bfloat16*)take((size_t)E_EXP * HDIM * CDIM * 2); // [E][3072][768]
  __hip_bfloat16* wprT = (__hip_bfloat16*)take((size_t)E_EXP * CDIM * HDIM * 2); // [E][768][3072]
  __hip_bfloat16* xin  = (__hip_bfloat16*)take((size_t)E_EXP * CAPC * CDIM * 2); // [E][CAP][768]
  __hip_bfloat16* hbuf = (__hip_bfloat16*)take((size_t)E_EXP * CAPC * HDIM * 2); // [E][CAP][3072]
  float*          eout = (float*)take((size_t)E_EXP * CAPC * CDIM * 4);          // [E][CAP][768]
  int*   eidx = (int*)take((size_t)2 * N_TOK * 4);
  float* pv   = (float*)take((size_t)2 * N_TOK * 4);
  int*   slot = (int*)take((size_t)2 * N_TOK * 4);
  int*   stok = (int*)take((size_t)E_EXP * CAPC * 4);
  int*   ecnt = (int*)take((size_t)E_EXP * 4);

  hipFuncSetAttribute((const void*)gemmT<1, 256, CDIM, 12>,
                      hipFuncAttributeMaxDynamicSharedMemorySize, 131072);
  hipFuncSetAttribute((const void*)gemm2b,
                      hipFuncAttributeMaxDynamicSharedMemorySize, 65536);

  // weight transpose+convert
  transpose_convert<<<dim3(HDIM / 32, CDIM / 32, E_EXP), 256, 0, stream>>>(cfc, wfcT, CDIM, HDIM);
  transpose_convert<<<dim3(CDIM / 32, HDIM / 32, E_EXP), 256, 0, stream>>>(cpr, wprT, HDIM, CDIM);

  router_kernel<<<N_TOK / 4, 256, 0, stream>>>(x, wg, eidx, pv);
  init_slots<<<(E_EXP * CAPC) / 256, 256, 0, stream>>>(stok);
  scan_kernel<<<1, 256, 0, stream>>>(eidx, slot, stok, ecnt);
  dispatch_kernel<<<(E_EXP * CAPC) / 4, 256, 0, stream>>>(x, stok, xin);

  // GEMM1 + bias + exact GELU -> h (bf16): per-expert M=2048 (only used rows),
  // N=3072, K=768; 256x256 tile, grid 768 (1 expert/XCD), ~62% tiles active.
  gemmT<1, 256, CDIM, 12><<<768, 512, 131072, stream>>>(xin, wfcT, fcb, hbuf, ecnt);
  // GEMM2 + bias -> exp_out (f32): per-expert M=2048 (used rows), N=768, K=3072;
  // 128x128 tile, 96 tiles/expert, grid 768 = 3 blocks/CU, ~53% tiles active.
  gemm2b<<<768, 256, 65536, stream>>>(hbuf, wprT, prb, eout, CAPC, CDIM, HDIM, 6, 16, ecnt);

  combine_kernel<<<N_TOK / 4, 256, 0, stream>>>(eout, eidx, pv, slot, out);
}

// Round 9
// 200.252 us; speedup vs baseline: 2.0863x; 1.0212x over previous
//
#include <hip/hip_runtime.h>
#include <hip/hip_bf16.h>
#include <math.h>

// Problem constants (B=4, T=1024, C=768, E=8, K=2)
#define N_TOK 4096
#define CDIM  768
#define E_EXP 8
#define CAPC  2048
#define HDIM  3072   // 4*C

typedef __attribute__((ext_vector_type(8))) short short8;
typedef __attribute__((ext_vector_type(4))) float floatx4;

#define VMCNT(n) asm volatile("s_waitcnt vmcnt(" #n ")" ::: "memory")
#define LGKM(n)  asm volatile("s_waitcnt lgkmcnt(" #n ")" ::: "memory")
#define SB0()    __builtin_amdgcn_sched_barrier(0)

static __device__ __forceinline__ unsigned short f2bf(float f) {
  __hip_bfloat16 h = __float2bfloat16(f);
  return __builtin_bit_cast(unsigned short, h);
}

// ---------------------------------------------------------------------------
// K1: transpose + f32->bf16 convert.  in: [E][R][Cc] f32 -> out: [E][Cc][R] bf16
// ---------------------------------------------------------------------------
__global__ __launch_bounds__(256)
void transpose_convert(const float* __restrict__ in, __hip_bfloat16* __restrict__ out,
                       int R, int Cc)
{
  __shared__ float tile[32][33];
  const int e  = blockIdx.z;
  const int c0 = blockIdx.x * 32;
  const int r0 = blockIdx.y * 32;
  const float* ie = in + (size_t)e * R * Cc;
  __hip_bfloat16* oe = out + (size_t)e * Cc * R;
  const int t = threadIdx.x;
  {
    const int r = t >> 3, c = (t & 7) * 4;
    const float4 v = *(const float4*)(ie + (size_t)(r0 + r) * Cc + c0 + c);
    tile[r][c + 0] = v.x; tile[r][c + 1] = v.y; tile[r][c + 2] = v.z; tile[r][c + 3] = v.w;
  }
  __syncthreads();
  {
    const int cc = t >> 3, rr = (t & 7) * 4;
    ushort4 o;
    o.x = f2bf(tile[rr + 0][cc]);
    o.y = f2bf(tile[rr + 1][cc]);
    o.z = f2bf(tile[rr + 2][cc]);
    o.w = f2bf(tile[rr + 3][cc]);
    *(ushort4*)((unsigned short*)oe + (size_t)(c0 + cc) * R + r0 + rr) = o;
  }
}

// ---------------------------------------------------------------------------
// K2: router — logits = x @ w_g^T, top-2 + softmax over the two kept logits.
// ---------------------------------------------------------------------------
__global__ __launch_bounds__(256)
void router_kernel(const float* __restrict__ x, const float* __restrict__ wg,
                   int* __restrict__ eidx, float* __restrict__ pval)
{
  const int wv = threadIdx.x >> 6, lane = threadIdx.x & 63;
  const int n = blockIdx.x * 4 + wv;
  const float* xr = x + (size_t)n * CDIM;
  float acc[E_EXP] = {0.f, 0.f, 0.f, 0.f, 0.f, 0.f, 0.f, 0.f};
#pragma unroll
  for (int i = 0; i < CDIM / 64; ++i) {
    const float xv = xr[i * 64 + lane];
#pragma unroll
    for (int e = 0; e < E_EXP; ++e)
      acc[e] = fmaf(xv, wg[e * CDIM + i * 64 + lane], acc[e]);
  }
#pragma unroll
  for (int e = 0; e < E_EXP; ++e) {
#pragma unroll
    for (int off = 32; off > 0; off >>= 1)
      acc[e] += __shfl_xor(acc[e], off);
  }
  if (lane == 0) {
    int e0 = 0; float v0 = acc[0];
#pragma unroll
    for (int e = 1; e < E_EXP; ++e) if (acc[e] > v0) { v0 = acc[e]; e0 = e; }
    int e1 = -1; float v1 = -3.4e38f;
#pragma unroll
    for (int e = 0; e < E_EXP; ++e) if (e != e0 && acc[e] > v1) { v1 = acc[e]; e1 = e; }
    const float ex = __expf(v1 - v0);
    const float inv = 1.f / (1.f + ex);
    eidx[n] = e0; eidx[N_TOK + n] = e1;
    pval[n] = inv; pval[N_TOK + n] = ex * inv;
  }
}

// ---------------------------------------------------------------------------
// K3: init slot_token to -1
// ---------------------------------------------------------------------------
__global__ void init_slots(int* __restrict__ p)
{
  p[blockIdx.x * 256 + threadIdx.x] = -1;
}

// ---------------------------------------------------------------------------
// K4: capacity scan (k-major reference order), single block Hillis-Steele.
// Emits ecnt[e] and compact active-tile work lists for both GEMMs:
//   work1: (e<<8|by) for by in [0, ceil(ecnt/256))   (<=64 entries)
//   work2: (e<<8|by) for by in [0, ceil(ecnt/128))   (<=128 entries)
//   wcnt[0] = npairs1*12 (gemm1 items), wcnt[1] = npairs2*6 (gemm2 items)
// ---------------------------------------------------------------------------
__global__ __launch_bounds__(256)
void scan_kernel(const int* __restrict__ eidx, int* __restrict__ slot,
                 int* __restrict__ slot_token, int* __restrict__ ecnt,
                 int* __restrict__ work1, int* __restrict__ work2,
                 int* __restrict__ wcnt)
{
  const int t = threadIdx.x;
  const int base = t * 32;
  int e_local[32];
  int cnt[E_EXP] = {0, 0, 0, 0, 0, 0, 0, 0};
#pragma unroll
  for (int i = 0; i < 32; ++i) {
    const int e = eidx[base + i];
    e_local[i] = e;
    cnt[e]++;
  }
  __shared__ int hist[256][E_EXP];
  __shared__ int secnt[E_EXP];
#pragma unroll
  for (int e = 0; e < E_EXP; ++e) hist[t][e] = cnt[e];
  __syncthreads();
  for (int off = 1; off < 256; off <<= 1) {
    int v[E_EXP] = {0, 0, 0, 0, 0, 0, 0, 0};
    if (t >= off) {
#pragma unroll
      for (int e = 0; e < E_EXP; ++e) v[e] = hist[t - off][e];
    }
    __syncthreads();
    if (t >= off) {
#pragma unroll
      for (int e = 0; e < E_EXP; ++e) hist[t][e] += v[e];
    }
    __syncthreads();
  }
  if (t == 255) {
#pragma unroll
    for (int e = 0; e < E_EXP; ++e) {
      const int tot = hist[255][e];
      const int c = tot < CAPC ? tot : CAPC;
      ecnt[e] = c;
      secnt[e] = c;
    }
  }
  __syncthreads();
  if (t == 0) {
    int n1 = 0, n2 = 0;
    for (int e = 0; e < E_EXP; ++e) {
      const int c = secnt[e];
      const int t1 = (c + 255) >> 8;
      for (int b = 0; b < t1; ++b) work1[n1++] = (e << 8) | b;
      const int t2 = (c + 127) >> 7;
      for (int b = 0; b < t2; ++b) work2[n2++] = (e << 8) | b;
    }
    wcnt[0] = n1 * 12;
    wcnt[1] = n2 * 6;
  }
  int run[E_EXP];
#pragma unroll
  for (int e = 0; e < E_EXP; ++e) run[e] = hist[t][e] - cnt[e];
#pragma unroll
  for (int i = 0; i < 32; ++i) {
    const int a = base + i;
    const int e = e_local[i];
    const int r = run[e]++;
    const int s = (r < CAPC) ? r : -1;
    slot[a] = s;
    if (s >= 0) slot_token[e * CAPC + s] = (a < N_TOK) ? a : (a - N_TOK);
  }
}

// ---------------------------------------------------------------------------
// K5: dispatch — exp_in row = bf16(x[token]); unused slots left untouched
// (their expert outputs are never read by combine: rank < count always).
// ---------------------------------------------------------------------------
__global__ __launch_bounds__(256)
void dispatch_kernel(const float* __restrict__ x, const int* __restrict__ slot_token,
                     __hip_bfloat16* __restrict__ xin)
{
  const int wv = threadIdx.x >> 6, lane = threadIdx.x & 63;
  const int s = blockIdx.x * 4 + wv;
  const int n = slot_token[s];
  if (n < 0) return;
  unsigned short* orow = (unsigned short*)xin + (size_t)s * CDIM;
  const float4* xr = (const float4*)(x + (size_t)n * CDIM);
#pragma unroll
  for (int i = 0; i < 3; ++i) {
    const float4 v = xr[i * 64 + lane];
    ushort4 o;
    o.x = f2bf(v.x); o.y = f2bf(v.y); o.z = f2bf(v.z); o.w = f2bf(v.w);
    *(ushort4*)(orow + (size_t)(i * 64 + lane) * 4) = o;
  }
}

// ---------------------------------------------------------------------------
// K6a: GEMM1 — 256x256 tile, BK=64, 8 waves (2Mx4N), compile-time addressing,
// register-reuse phases, counted vmcnt depth-2, 2 barriers/tile
// + compacted work list with count-balanced XCD chunking.
// ---------------------------------------------------------------------------
template<int BN, int Kc>
__device__ __forceinline__ void stageT(const __hip_bfloat16* __restrict__ Ae,
                                       const __hip_bfloat16* __restrict__ Be,
                                       char* dst, int kt, int wv, int lane)
{
  constexpr int NI = BN / 64;
  const int r = wv * 8 + (lane >> 3);
  const int kb = ((lane & 7) * 16) ^ ((r & 7) << 4);   // pre-swizzled source
  const char* As = (const char*)Ae + (size_t)kt * 128 + (size_t)r * (Kc * 2) + kb;
  const char* Bs = (const char*)Be + (size_t)kt * 128 + (size_t)r * (Kc * 2) + kb;
#pragma unroll
  for (int j = 0; j < 4; ++j)
    __builtin_amdgcn_global_load_lds(
        (const __attribute__((address_space(1))) unsigned int*)(As + (size_t)j * 64 * Kc * 2),
        (__attribute__((address_space(3))) unsigned int*)(dst + j * 8192 + wv * 1024), 16, 0, 0);
#pragma unroll
  for (int j = 0; j < NI; ++j)
    __builtin_amdgcn_global_load_lds(
        (const __attribute__((address_space(1))) unsigned int*)(Bs + (size_t)j * 64 * Kc * 2),
        (__attribute__((address_space(3))) unsigned int*)(dst + 32768 + j * 8192 + wv * 1024), 16, 0, 0);
}

template<int BN, int Kc, int VME, bool ST, int BUF>
__device__ __forceinline__ void ktileT(int kt, char* lds,
                                       const __hip_bfloat16* __restrict__ Ae,
                                       const __hip_bfloat16* __restrict__ Be,
                                       floatx4 (&acc)[8][BN / 64],
                                       int wm, int wn, int fr, int fk, int wv, int lane)
{
  constexpr int NI = BN / 64;
  constexpr int BUFS = (256 + BN) * 128;
  if constexpr (VME == 8) VMCNT(8);
  else if constexpr (VME == 7) VMCNT(7);
  else VMCNT(0);
  SB0();
  __builtin_amdgcn_s_barrier();
  SB0();
  const char* bufA = lds + BUF * BUFS;
  const char* bufB = bufA + 32768;
  short8 a[4][2], b[NI][2];

  // ---- p0: read A0 + b[0..1], MFMA A0 x b01 ----
#pragma unroll
  for (int mi = 0; mi < 4; ++mi) {
    const int lr = wm * 128 + mi * 16 + fr;
#pragma unroll
    for (int kk = 0; kk < 2; ++kk)
      a[mi][kk] = *(const short8*)(bufA + lr * 128 + ((kk * 64 + fk * 16) ^ ((lr & 7) << 4)));
  }
#pragma unroll
  for (int ni = 0; ni < 2; ++ni) {
    const int lj = wn * (BN / 4) + ni * 16 + fr;
#pragma unroll
    for (int kk = 0; kk < 2; ++kk)
      b[ni][kk] = *(const short8*)(bufB + lj * 128 + ((kk * 64 + fk * 16) ^ ((lj & 7) << 4)));
  }
  __builtin_amdgcn_s_setprio(1);
#pragma unroll
  for (int kk = 0; kk < 2; ++kk)
#pragma unroll
    for (int mi = 0; mi < 4; ++mi)
#pragma unroll
      for (int ni = 0; ni < 2; ++ni)
        acc[mi][ni] = __builtin_amdgcn_mfma_f32_16x16x32_bf16(a[mi][kk], b[ni][kk], acc[mi][ni], 0, 0, 0);
  __builtin_amdgcn_s_setprio(0);
  SB0();

  // ---- p1: read b[2..NI-1], MFMA A0 x bhi ----
#pragma unroll
  for (int ni = 2; ni < NI; ++ni) {
    const int lj = wn * (BN / 4) + ni * 16 + fr;
#pragma unroll
    for (int kk = 0; kk < 2; ++kk)
      b[ni][kk] = *(const short8*)(bufB + lj * 128 + ((kk * 64 + fk * 16) ^ ((lj & 7) << 4)));
  }
  __builtin_amdgcn_s_setprio(1);
#pragma unroll
  for (int kk = 0; kk < 2; ++kk)
#pragma unroll
    for (int mi = 0; mi < 4; ++mi)
#pragma unroll
      for (int ni = 2; ni < NI; ++ni)
        acc[mi][ni] = __builtin_amdgcn_mfma_f32_16x16x32_bf16(a[mi][kk], b[ni][kk], acc[mi][ni], 0, 0, 0);
  __builtin_amdgcn_s_setprio(0);
  SB0();

  // ---- p2: read A1 (overwrite a), MFMA A1 x b01 ----
#pragma unroll
  for (int mi = 0; mi < 4; ++mi) {
    const int lr = wm * 128 + 64 + mi * 16 + fr;
#pragma unroll
    for (int kk = 0; kk < 2; ++kk)
      a[mi][kk] = *(const short8*)(bufA + lr * 128 + ((kk * 64 + fk * 16) ^ ((lr & 7) << 4)));
  }
  __builtin_amdgcn_s_setprio(1);
#pragma unroll
  for (int kk = 0; kk < 2; ++kk)
#pragma unroll
    for (int mi = 0; mi < 4; ++mi)
#pragma unroll
      for (int ni = 0; ni < 2; ++ni)
        acc[4 + mi][ni] = __builtin_amdgcn_mfma_f32_16x16x32_bf16(a[mi][kk], b[ni][kk], acc[4 + mi][ni], 0, 0, 0);
  __builtin_amdgcn_s_setprio(0);
  SB0();
  __builtin_amdgcn_s_barrier();     // all waves done reading buf[BUF]
  SB0();
  if constexpr (ST)
    stageT<BN, Kc>(Ae, Be, lds + BUF * BUFS, kt + 2, wv, lane);
  SB0();

  // ---- p3: MFMA A1 x bhi (registers only, overlaps stage issue) ----
  __builtin_amdgcn_s_setprio(1);
#pragma unroll
  for (int kk = 0; kk < 2; ++kk)
#pragma unroll
    for (int mi = 0; mi < 4; ++mi)
#pragma unroll
      for (int ni = 2; ni < NI; ++ni)
        acc[4 + mi][ni] = __builtin_amdgcn_mfma_f32_16x16x32_bf16(a[mi][kk], b[ni][kk], acc[4 + mi][ni], 0, 0, 0);
  __builtin_amdgcn_s_setprio(0);
  SB0();
}

template<int GELU_OUT, int BN, int Kc, int NBX>
__global__ __launch_bounds__(512, 2)
void gemmT(const __hip_bfloat16* __restrict__ A, const __hip_bfloat16* __restrict__ Bt,
           const float* __restrict__ bias, void* __restrict__ Cout,
           const int* __restrict__ work, const int* __restrict__ wcnt)
{
  constexpr int NI  = BN / 64;
  constexpr int L   = 4 + NI;
  constexpr int Nc  = NBX * BN;
  constexpr int ntk = Kc / 64;
  constexpr int BUFS = (256 + BN) * 128;
  extern __shared__ __align__(16) char lds[];

  // count-balanced XCD chunking over the compacted work list
  const int T = wcnt[0];
  const int bId = blockIdx.x;
  const int cpx = (T + 7) >> 3;
  if ((bId >> 3) >= cpx) return;
  const int idx = (bId & 7) * cpx + (bId >> 3);
  if (idx >= T) return;
  const int p = idx / NBX, bx = idx % NBX;
  const int w = work[p];
  const int e = w >> 8, by = w & 255;

  const int t = threadIdx.x, wv = t >> 6, lane = t & 63;
  const int wm = wv >> 2, wn = wv & 3;
  const int fr = lane & 15, fk = lane >> 4;

  const __hip_bfloat16* Ae = A + (size_t)e * CAPC * Kc + (size_t)by * 256 * Kc;
  const __hip_bfloat16* Be = Bt + (size_t)e * Nc * Kc + (size_t)bx * BN * Kc;

  floatx4 acc[8][NI] = {};

  stageT<BN, Kc>(Ae, Be, lds, 0, wv, lane);
  stageT<BN, Kc>(Ae, Be, lds + BUFS, 1, wv, lane);
  SB0();

#pragma unroll 1
  for (int kt = 0; kt < ntk - 2; kt += 2) {
    ktileT<BN, Kc, L, true, 0>(kt, lds, Ae, Be, acc, wm, wn, fr, fk, wv, lane);
    ktileT<BN, Kc, L, true, 1>(kt + 1, lds, Ae, Be, acc, wm, wn, fr, fk, wv, lane);
  }
  ktileT<BN, Kc, L, false, 0>(ntk - 2, lds, Ae, Be, acc, wm, wn, fr, fk, wv, lane);
  ktileT<BN, Kc, 0, false, 1>(ntk - 1, lds, Ae, Be, acc, wm, wn, fr, fk, wv, lane);

  const float* be = bias + (size_t)e * Nc;
  const size_t cbase = (size_t)e * CAPC * Nc;
  const int m0 = by * 256, n0 = bx * BN;

  if constexpr (GELU_OUT) {
    unsigned short* ep = (unsigned short*)(lds + wv * 2048);
    unsigned short* Cb = (unsigned short*)Cout + cbase;
    float bcol[NI];
#pragma unroll
    for (int ni = 0; ni < NI; ++ni) bcol[ni] = be[n0 + wn * (BN / 4) + ni * 16 + fr];
#pragma unroll
    for (int mi = 0; mi < 8; ++mi) {
#pragma unroll
      for (int ni = 0; ni < NI; ++ni)
#pragma unroll
        for (int j = 0; j < 4; ++j) {
          float v = acc[mi][ni][j] + bcol[ni];
          v = 0.5f * v * (1.0f + erff(v * 0.70710678118654752f));
          const int row = fk * 4 + j;
          *(unsigned short*)((char*)ep + row * 128 + ((ni * 32 + fr * 2) ^ (fk << 5))) = f2bf(v);
        }
      LGKM(0); SB0();
      const int r = lane & 15;
      const int grow = m0 + wm * 128 + mi * 16 + r;
#pragma unroll
      for (int it = 0; it < 2; ++it) {
        const int q = (lane >> 4) + it * 4;
        const short8 vv = *(const short8*)((char*)ep + r * 128 + ((q * 16) ^ ((r >> 2) << 5)));
        *(short8*)(Cb + (size_t)grow * Nc + n0 + wn * 64 + q * 8) = vv;
      }
      LGKM(0); SB0();
    }
  } else {
#pragma unroll
    for (int ni = 0; ni < NI; ++ni) {
      const int col = n0 + wn * (BN / 4) + ni * 16 + fr;
      const float b = be[col];
#pragma unroll
      for (int mi = 0; mi < 8; ++mi) {
        const int rbase = m0 + wm * 128 + mi * 16 + fk * 4;
#pragma unroll
        for (int j = 0; j < 4; ++j) {
          ((float*)Cout)[cbase + (size_t)(rbase + j) * Nc + col] = acc[mi][ni][j] + b;
        }
      }
    }
  }
}

// ---------------------------------------------------------------------------
// K6b: GEMM2 — 128x128 tile, BK=64, 4 waves (2Mx2N), dbuf 64 KiB, 2 blk/CU
// + compacted work list with count-balanced XCD chunking.
// ---------------------------------------------------------------------------
__device__ __forceinline__ void stage_ab(const __hip_bfloat16* Ae, const __hip_bfloat16* Be,
                                         char* lds, int K, int kt, int isB,
                                         int wv, int lane)
{
  const char* src = (const char*)(isB ? Be : Ae);
  char* dst = lds + (kt & 1) * 32768 + isB * 16384;
#pragma unroll
  for (int j = 0; j < 4; ++j) {
    const int li = j * 32 + wv * 8 + (lane >> 3);
    const int kb = ((lane & 7) * 16) ^ ((li & 7) << 4);  // pre-swizzled source
    const char* g = src + ((size_t)li * K + (size_t)kt * 64) * 2 + kb;
    char* lp = dst + j * 4096 + wv * 1024;
    __builtin_amdgcn_global_load_lds((const __attribute__((address_space(1))) unsigned int*)g,
                                     (__attribute__((address_space(3))) unsigned int*)lp, 16, 0, 0);
  }
}

template<int VME, bool S2>
__device__ __forceinline__ void ktile2(int kt, char* lds,
                                       const __hip_bfloat16* Ae, const __hip_bfloat16* Be,
                                       int K, floatx4 (&acc)[4][4],
                                       int wm, int wn, int fr, int fk, int wv, int lane)
{
  if constexpr (VME == 8) VMCNT(8); else VMCNT(0);
  __builtin_amdgcn_s_barrier();
  SB0();
  const char* bufA = lds + ((kt & 1) ? 32768 : 0);
  const char* bufB = bufA + 16384;
  short8 a[4][2], b[4][2];
#pragma unroll
  for (int mi = 0; mi < 4; ++mi) {
    const int lr = wm * 64 + mi * 16 + fr;
    a[mi][0] = *(const short8*)(bufA + lr * 128 + ((fk * 16) ^ ((lr & 7) << 4)));
  }
#pragma unroll
  for (int ni = 0; ni < 4; ++ni) {
    const int lj = wn * 64 + ni * 16 + fr;
    b[ni][0] = *(const short8*)(bufB + lj * 128 + ((fk * 16) ^ ((lj & 7) << 4)));
  }
  SB0();
#pragma unroll
  for (int mi = 0; mi < 4; ++mi) {
    const int lr = wm * 64 + mi * 16 + fr;
    a[mi][1] = *(const short8*)(bufA + lr * 128 + ((64 + fk * 16) ^ ((lr & 7) << 4)));
  }
#pragma unroll
  for (int ni = 0; ni < 4; ++ni) {
    const int lj = wn * 64 + ni * 16 + fr;
    b[ni][1] = *(const short8*)(bufB + lj * 128 + ((64 + fk * 16) ^ ((lj & 7) << 4)));
  }
  SB0();
  LGKM(8); SB0();
  __builtin_amdgcn_s_setprio(1);
#pragma unroll
  for (int mi = 0; mi < 4; ++mi)
#pragma unroll
    for (int ni = 0; ni < 4; ++ni)
      acc[mi][ni] = __builtin_amdgcn_mfma_f32_16x16x32_bf16(a[mi][0], b[ni][0], acc[mi][ni], 0, 0, 0);
  __builtin_amdgcn_s_setprio(0);
  SB0();
  LGKM(0); SB0();
  __builtin_amdgcn_s_setprio(1);
#pragma unroll
  for (int mi = 0; mi < 4; ++mi)
#pragma unroll
    for (int ni = 0; ni < 4; ++ni)
      acc[mi][ni] = __builtin_amdgcn_mfma_f32_16x16x32_bf16(a[mi][1], b[ni][1], acc[mi][ni], 0, 0, 0);
  __builtin_amdgcn_s_setprio(0);
  SB0();
  __builtin_amdgcn_s_barrier();
  if (S2) {
    stage_ab(Ae, Be, lds, K, kt + 2, 0, wv, lane);
    stage_ab(Ae, Be, lds, K, kt + 2, 1, wv, lane);
  }
  SB0();
}

__global__ __launch_bounds__(256, 2)
void gemm2b(const __hip_bfloat16* __restrict__ A, const __hip_bfloat16* __restrict__ Bt,
            const float* __restrict__ bias, float* __restrict__ Cout,
            int M, int Nn, int K,
            const int* __restrict__ work, const int* __restrict__ wcnt)
{
  extern __shared__ __align__(16) char lds[];
  const int T = wcnt[1];
  const int bId = blockIdx.x;
  const int cpx = (T + 7) >> 3;
  if ((bId >> 3) >= cpx) return;
  const int idx = (bId & 7) * cpx + (bId >> 3);
  if (idx >= T) return;
  const int p = idx / 6, bx = idx % 6;
  const int w = work[p];
  const int e = w >> 8, by = w & 255;

  const int t = threadIdx.x, wv = t >> 6, lane = t & 63;
  const int wm = wv >> 1, wn = wv & 1;
  const int fr = lane & 15, fk = lane >> 4;
  const int ntk = K >> 6;

  const __hip_bfloat16* Ae = A + (size_t)e * M * K + (size_t)by * 128 * K;
  const __hip_bfloat16* Be = Bt + (size_t)e * Nn * K + (size_t)bx * 128 * K;

  floatx4 acc[4][4] = {};

  stage_ab(Ae, Be, lds, K, 0, 0, wv, lane);
  stage_ab(Ae, Be, lds, K, 0, 1, wv, lane);
  stage_ab(Ae, Be, lds, K, 1, 0, wv, lane);
  stage_ab(Ae, Be, lds, K, 1, 1, wv, lane);
  SB0();

  for (int kt = 0; kt < ntk - 2; ++kt)
    ktile2<8, true>(kt, lds, Ae, Be, K, acc, wm, wn, fr, fk, wv, lane);
  ktile2<8, false>(ntk - 2, lds, Ae, Be, K, acc, wm, wn, fr, fk, wv, lane);
  ktile2<0, false>(ntk - 1, lds, Ae, Be, K, acc, wm, wn, fr, fk, wv, lane);

  const float* be = bias + (size_t)e * Nn;
  const size_t cbase = (size_t)e * M * Nn;
  const int m0 = by * 128, n0 = bx * 128;
#pragma unroll
  for (int ni = 0; ni < 4; ++ni) {
    const int col = n0 + wn * 64 + ni * 16 + fr;
    const float b = be[col];
#pragma unroll
    for (int mi = 0; mi < 4; ++mi) {
      const int rbase = m0 + wm * 64 + mi * 16 + fk * 4;
#pragma unroll
      for (int j = 0; j < 4; ++j) {
        Cout[cbase + (size_t)(rbase + j) * Nn + col] = acc[mi][ni][j] + b;
      }
    }
  }
}

// ---------------------------------------------------------------------------
// K7: combine — out[n] = w0*exp_out[e0][s0] + w1*exp_out[e1][s1]
// ---------------------------------------------------------------------------
__global__ __launch_bounds__(256)
void combine_kernel(const float* __restrict__ eout, const int* __restrict__ eidx,
                    const float* __restrict__ pval, const int* __restrict__ slot,
                    float* __restrict__ out)
{
  const int wv = threadIdx.x >> 6, lane = threadIdx.x & 63;
  const int n = blockIdx.x * 4 + wv;
  const int e0 = eidx[n], e1 = eidx[N_TOK + n];
  int s0 = slot[n], s1 = slot[N_TOK + n];
  const float w0 = (s0 >= 0) ? pval[n] : 0.f;
  const float w1 = (s1 >= 0) ? pval[N_TOK + n] : 0.f;
  s0 = (s0 >= 0) ? s0 : 0;
  s1 = (s1 >= 0) ? s1 : 0;
  const float4* r0 = (const float4*)(eout + ((size_t)e0 * CAPC + s0) * CDIM);
  const float4* r1 = (const float4*)(eout + ((size_t)e1 * CAPC + s1) * CDIM);
  float4* o = (float4*)(out + (size_t)n * CDIM);
#pragma unroll
  for (int i = 0; i < 3; ++i) {
    const float4 a = r0[i * 64 + lane];
    const float4 b = r1[i * 64 + lane];
    float4 c;
    c.x = w0 * a.x + w1 * b.x;
    c.y = w0 * a.y + w1 * b.y;
    c.z = w0 * a.z + w1 * b.z;
    c.w = w0 * a.w + w1 * b.w;
    o[i * 64 + lane] = c;
  }
}

// ---------------------------------------------------------------------------
extern "C" void kernel_launch(void* const* d_in, const int* in_sizes, int n_in,
                              void* d_out, int out_size, void* d_ws, size_t ws_size,
                              hipStream_t stream)
{
  const float* x   = (const float*)d_in[0];
  const float* wg  = (const float*)d_in[1];
  const float* cfc = (const float*)d_in[2];
  const float* fcb = (const float*)d_in[3];
  const float* cpr = (const float*)d_in[4];
  const float* prb = (const float*)d_in[5];
  float* out = (float*)d_out;

  char* ws = (char*)d_ws;
  size_t off = 0;
  auto take = [&](size_t bytes) -> void* {
    void* p = ws + off;
    off += (bytes + 255) & ~(size_t)255;
    return p;
  };
  __hip_bfloat16* wfcT = (__hip_bfloat16*)take((size_t)E_EXP * HDIM * CDIM * 2); // [E][3072][768]
  __hip_bfloat16* wprT = (__hip_bfloat16*)take((size_t)E_EXP * CDIM * HDIM * 2); // [E][768][3072]
  __hip_bfloat16* xin  = (__hip_bfloat16*)take((size_t)E_EXP * CAPC * CDIM * 2); // [E][CAP][768]
  __hip_bfloat16* hbuf = (__hip_bfloat16*)take((size_t)E_EXP * CAPC * HDIM * 2); // [E][CAP][3072]
  float*          eout = (float*)take((size_t)E_EXP * CAPC * CDIM * 4);          // [E][CAP][768]
  int*   eidx = (int*)take((size_t)2 * N_TOK * 4);
  float* pv   = (float*)take((size_t)2 * N_TOK * 4);
  int*   slot = (int*)take((size_t)2 * N_TOK * 4);
  int*   stok = (int*)take((size_t)E_EXP * CAPC * 4);
  int*   ecnt = (int*)take((size_t)E_EXP * 4);
  int*   work1 = (int*)take((size_t)64 * 4);
  int*   work2 = (int*)take((size_t)128 * 4);
  int*   wcnt = (int*)take((size_t)2 * 4);

  hipFuncSetAttribute((const void*)gemmT<1, 256, CDIM, 12>,
                      hipFuncAttributeMaxDynamicSharedMemorySize, 131072);
  hipFuncSetAttribute((const void*)gemm2b,
                      hipFuncAttributeMaxDynamicSharedMemorySize, 65536);

  // weight transpose+convert
  transpose_convert<<<dim3(HDIM / 32, CDIM / 32, E_EXP), 256, 0, stream>>>(cfc, wfcT, CDIM, HDIM);
  transpose_convert<<<dim3(CDIM / 32, HDIM / 32, E_EXP), 256, 0, stream>>>(cpr, wprT, HDIM, CDIM);

  router_kernel<<<N_TOK / 4, 256, 0, stream>>>(x, wg, eidx, pv);
  init_slots<<<(E_EXP * CAPC) / 256, 256, 0, stream>>>(stok);
  scan_kernel<<<1, 256, 0, stream>>>(eidx, slot, stok, ecnt, work1, work2, wcnt);
  dispatch_kernel<<<(E_EXP * CAPC) / 4, 256, 0, stream>>>(x, stok, xin);

  // GEMM1 + bias + exact GELU -> h (bf16): compacted active 256-row tiles,
  // count-balanced across XCDs; N=3072, K=768.
  gemmT<1, 256, CDIM, 12><<<768, 512, 131072, stream>>>(xin, wfcT, fcb, hbuf, work1, wcnt);
  // GEMM2 + bias -> exp_out (f32): compacted active 128-row tiles, balanced;
  // N=768, K=3072, 128x128 tile, 2 blocks/CU.
  gemm2b<<<768, 256, 65536, stream>>>(hbuf, wprT, prb, eout, CAPC, CDIM, HDIM, work2, wcnt);

  combine_kernel<<<N_TOK / 4, 256, 0, stream>>>(eout, eidx, pv, slot, out);
}

// Round 10
// 185.940 us; speedup vs baseline: 2.2469x; 1.0770x over previous
//
#include <hip/hip_runtime.h>
#include <hip/hip_bf16.h>
#include <math.h>

// Problem constants (B=4, T=1024, C=768, E=8, K=2)
#define N_TOK 4096
#define CDIM  768
#define E_EXP 8
#define CAPC  2048
#define HDIM  3072   // 4*C

typedef __attribute__((ext_vector_type(8))) short short8;
typedef __attribute__((ext_vector_type(4))) float floatx4;

#define VMCNT(n) asm volatile("s_waitcnt vmcnt(" #n ")" ::: "memory")
#define LGKM(n)  asm volatile("s_waitcnt lgkmcnt(" #n ")" ::: "memory")
#define SB0()    __builtin_amdgcn_sched_barrier(0)

static __device__ __forceinline__ unsigned short f2bf(float f) {
  __hip_bfloat16 h = __float2bfloat16(f);
  return __builtin_bit_cast(unsigned short, h);
}
static __device__ __forceinline__ float bf2f(unsigned short u) {
  return __builtin_bit_cast(float, (unsigned int)u << 16);
}

// ---------------------------------------------------------------------------
// K1: transpose + f32->bf16 convert, 64x64 tiles.
// in: [E][R][Cc] f32 -> out: [E][Cc][R] bf16
// ---------------------------------------------------------------------------
__global__ __launch_bounds__(256)
void transpose64(const float* __restrict__ in, __hip_bfloat16* __restrict__ out,
                 int R, int Cc)
{
  __shared__ float tile[64][65];
  const int e  = blockIdx.z;
  const int c0 = blockIdx.x * 64;
  const int r0 = blockIdx.y * 64;
  const float* ie = in + (size_t)e * R * Cc;
  unsigned short* oe = (unsigned short*)out + (size_t)e * Cc * R;
  const int t = threadIdx.x;
  {
    const int r = t >> 2, c = (t & 3) * 4;   // lanes 0-3 cover cols 0-15 contiguous
#pragma unroll
    for (int i = 0; i < 4; ++i) {
      const float4 v = *(const float4*)(ie + (size_t)(r0 + r) * Cc + c0 + c + i * 16);
      tile[r][c + i * 16 + 0] = v.x; tile[r][c + i * 16 + 1] = v.y;
      tile[r][c + i * 16 + 2] = v.z; tile[r][c + i * 16 + 3] = v.w;
    }
  }
  __syncthreads();
  {
    const int cc = t >> 2, rq = (t & 3) * 16;
    unsigned short o[16];
#pragma unroll
    for (int i = 0; i < 16; ++i) o[i] = f2bf(tile[rq + i][cc]);
    unsigned short* dst = oe + (size_t)(c0 + cc) * R + r0 + rq;
    *(short8*)(dst)     = *(short8*)&o[0];
    *(short8*)(dst + 8) = *(short8*)&o[8];
  }
}

// ---------------------------------------------------------------------------
// K2: router — logits = x @ w_g^T, top-2 + softmax over the two kept logits.
// ---------------------------------------------------------------------------
__global__ __launch_bounds__(256)
void router_kernel(const float* __restrict__ x, const float* __restrict__ wg,
                   int* __restrict__ eidx, float* __restrict__ pval)
{
  const int wv = threadIdx.x >> 6, lane = threadIdx.x & 63;
  const int n = blockIdx.x * 4 + wv;
  const float* xr = x + (size_t)n * CDIM;
  float acc[E_EXP] = {0.f, 0.f, 0.f, 0.f, 0.f, 0.f, 0.f, 0.f};
#pragma unroll
  for (int i = 0; i < CDIM / 64; ++i) {
    const float xv = xr[i * 64 + lane];
#pragma unroll
    for (int e = 0; e < E_EXP; ++e)
      acc[e] = fmaf(xv, wg[e * CDIM + i * 64 + lane], acc[e]);
  }
#pragma unroll
  for (int e = 0; e < E_EXP; ++e) {
#pragma unroll
    for (int off = 32; off > 0; off >>= 1)
      acc[e] += __shfl_xor(acc[e], off);
  }
  if (lane == 0) {
    int e0 = 0; float v0 = acc[0];
#pragma unroll
    for (int e = 1; e < E_EXP; ++e) if (acc[e] > v0) { v0 = acc[e]; e0 = e; }
    int e1 = -1; float v1 = -3.4e38f;
#pragma unroll
    for (int e = 0; e < E_EXP; ++e) if (e != e0 && acc[e] > v1) { v1 = acc[e]; e1 = e; }
    const float ex = __expf(v1 - v0);
    const float inv = 1.f / (1.f + ex);
    eidx[n] = e0; eidx[N_TOK + n] = e1;
    pval[n] = inv; pval[N_TOK + n] = ex * inv;
  }
}

// ---------------------------------------------------------------------------
// K4: capacity scan (k-major reference order), single block Hillis-Steele.
// Emits ecnt[e] and a compact 128-row-tile work list shared by both GEMMs:
//   work2: (e<<8|by128) for by128 in [0, ceil(ecnt/128))   (<=128 entries)
//   wcnt[0] = npairs*24 (gemm1 items), wcnt[1] = npairs*6 (gemm2 items)
// ---------------------------------------------------------------------------
__global__ __launch_bounds__(256)
void scan_kernel(const int* __restrict__ eidx, int* __restrict__ slot,
                 int* __restrict__ slot_token, int* __restrict__ ecnt,
                 int* __restrict__ work2, int* __restrict__ wcnt)
{
  const int t = threadIdx.x;
  const int base = t * 32;
  int e_local[32];
  int cnt[E_EXP] = {0, 0, 0, 0, 0, 0, 0, 0};
#pragma unroll
  for (int i = 0; i < 32; ++i) {
    const int e = eidx[base + i];
    e_local[i] = e;
    cnt[e]++;
  }
  __shared__ int hist[256][E_EXP];
  __shared__ int secnt[E_EXP];
#pragma unroll
  for (int e = 0; e < E_EXP; ++e) hist[t][e] = cnt[e];
  __syncthreads();
  for (int off = 1; off < 256; off <<= 1) {
    int v[E_EXP] = {0, 0, 0, 0, 0, 0, 0, 0};
    if (t >= off) {
#pragma unroll
      for (int e = 0; e < E_EXP; ++e) v[e] = hist[t - off][e];
    }
    __syncthreads();
    if (t >= off) {
#pragma unroll
      for (int e = 0; e < E_EXP; ++e) hist[t][e] += v[e];
    }
    __syncthreads();
  }
  if (t == 255) {
#pragma unroll
    for (int e = 0; e < E_EXP; ++e) {
      const int tot = hist[255][e];
      const int c = tot < CAPC ? tot : CAPC;
      ecnt[e] = c;
      secnt[e] = c;
    }
  }
  __syncthreads();
  if (t == 0) {
    int n2 = 0;
    for (int e = 0; e < E_EXP; ++e) {
      const int c = secnt[e];
      const int t2 = (c + 127) >> 7;
      for (int b = 0; b < t2; ++b) work2[n2++] = (e << 8) | b;
    }
    wcnt[0] = n2 * 24;
    wcnt[1] = n2 * 6;
  }
  int run[E_EXP];
#pragma unroll
  for (int e = 0; e < E_EXP; ++e) run[e] = hist[t][e] - cnt[e];
#pragma unroll
  for (int i = 0; i < 32; ++i) {
    const int a = base + i;
    const int e = e_local[i];
    const int r = run[e]++;
    const int s = (r < CAPC) ? r : -1;
    slot[a] = s;
    if (s >= 0) slot_token[e * CAPC + s] = (a < N_TOK) ? a : (a - N_TOK);
  }
}

// ---------------------------------------------------------------------------
// K5: dispatch — exp_in row = bf16(x[token]) for used slots only (bounds via
// ecnt; unused slots never read downstream).  One wave/slot.
// ---------------------------------------------------------------------------
__global__ __launch_bounds__(256)
void dispatch_kernel(const float* __restrict__ x, const int* __restrict__ slot_token,
                     const int* __restrict__ ecnt, __hip_bfloat16* __restrict__ xin)
{
  const int wv = threadIdx.x >> 6, lane = threadIdx.x & 63;
  const int s = blockIdx.x * 4 + wv;
  const int e = s >> 11;                 // CAPC = 2048
  if ((s & (CAPC - 1)) >= ecnt[e]) return;
  const int n = slot_token[s];
  unsigned short* orow = (unsigned short*)xin + (size_t)s * CDIM;
  const float4* xr = (const float4*)(x + (size_t)n * CDIM);
#pragma unroll
  for (int i = 0; i < 3; ++i) {
    const float4 v = xr[i * 64 + lane];
    ushort4 o;
    o.x = f2bf(v.x); o.y = f2bf(v.y); o.z = f2bf(v.z); o.w = f2bf(v.w);
    *(ushort4*)(orow + (size_t)(i * 64 + lane) * 4) = o;
  }
}

// ---------------------------------------------------------------------------
// K6: unified 128x128-tile batched GEMM, BK=64, 4 waves (2Mx2N, 64x64/wave),
// dbuf 64 KiB LDS -> 2 blocks/CU, counted vmcnt + counted LGKM (round-5/9
// proven body; matches its LDS-serial cycle model).
// Work-list mapping: idx -> pair p (expert e, 128-row by) x bx; serpentine bx
// order within a pair for cross-pair L2 reuse of B panels.
// Epilogue EPI=1: fast-exact GELU -> bf16; EPI=2: bias -> bf16.
// Both via LDS-staged coalesced stores (wave-private 2KB region).
// ---------------------------------------------------------------------------
__device__ __forceinline__ void stage_ab(const __hip_bfloat16* Ae, const __hip_bfloat16* Be,
                                         char* lds, int K, int kt, int isB,
                                         int wv, int lane)
{
  const char* src = (const char*)(isB ? Be : Ae);
  char* dst = lds + (kt & 1) * 32768 + isB * 16384;
#pragma unroll
  for (int j = 0; j < 4; ++j) {
    const int li = j * 32 + wv * 8 + (lane >> 3);
    const int kb = ((lane & 7) * 16) ^ ((li & 7) << 4);  // pre-swizzled source
    const char* g = src + ((size_t)li * K + (size_t)kt * 64) * 2 + kb;
    char* lp = dst + j * 4096 + wv * 1024;
    __builtin_amdgcn_global_load_lds((const __attribute__((address_space(1))) unsigned int*)g,
                                     (__attribute__((address_space(3))) unsigned int*)lp, 16, 0, 0);
  }
}

template<int VME, bool S2>
__device__ __forceinline__ void ktile2(int kt, char* lds,
                                       const __hip_bfloat16* Ae, const __hip_bfloat16* Be,
                                       int K, floatx4 (&acc)[4][4],
                                       int wm, int wn, int fr, int fk, int wv, int lane)
{
  if constexpr (VME == 8) VMCNT(8); else VMCNT(0);
  __builtin_amdgcn_s_barrier();
  SB0();
  const char* bufA = lds + ((kt & 1) ? 32768 : 0);
  const char* bufB = bufA + 16384;
  short8 a[4][2], b[4][2];
#pragma unroll
  for (int mi = 0; mi < 4; ++mi) {
    const int lr = wm * 64 + mi * 16 + fr;
    a[mi][0] = *(const short8*)(bufA + lr * 128 + ((fk * 16) ^ ((lr & 7) << 4)));
  }
#pragma unroll
  for (int ni = 0; ni < 4; ++ni) {
    const int lj = wn * 64 + ni * 16 + fr;
    b[ni][0] = *(const short8*)(bufB + lj * 128 + ((fk * 16) ^ ((lj & 7) << 4)));
  }
  SB0();
#pragma unroll
  for (int mi = 0; mi < 4; ++mi) {
    const int lr = wm * 64 + mi * 16 + fr;
    a[mi][1] = *(const short8*)(bufA + lr * 128 + ((64 + fk * 16) ^ ((lr & 7) << 4)));
  }
#pragma unroll
  for (int ni = 0; ni < 4; ++ni) {
    const int lj = wn * 64 + ni * 16 + fr;
    b[ni][1] = *(const short8*)(bufB + lj * 128 + ((64 + fk * 16) ^ ((lj & 7) << 4)));
  }
  SB0();
  LGKM(8); SB0();
  __builtin_amdgcn_s_setprio(1);
#pragma unroll
  for (int mi = 0; mi < 4; ++mi)
#pragma unroll
    for (int ni = 0; ni < 4; ++ni)
      acc[mi][ni] = __builtin_amdgcn_mfma_f32_16x16x32_bf16(a[mi][0], b[ni][0], acc[mi][ni], 0, 0, 0);
  __builtin_amdgcn_s_setprio(0);
  SB0();
  LGKM(0); SB0();
  __builtin_amdgcn_s_setprio(1);
#pragma unroll
  for (int mi = 0; mi < 4; ++mi)
#pragma unroll
    for (int ni = 0; ni < 4; ++ni)
      acc[mi][ni] = __builtin_amdgcn_mfma_f32_16x16x32_bf16(a[mi][1], b[ni][1], acc[mi][ni], 0, 0, 0);
  __builtin_amdgcn_s_setprio(0);
  SB0();
  __builtin_amdgcn_s_barrier();
  if (S2) {
    stage_ab(Ae, Be, lds, K, kt + 2, 0, wv, lane);
    stage_ab(Ae, Be, lds, K, kt + 2, 1, wv, lane);
  }
  SB0();
}

// fast exact-grade GELU: tanh form, |err| ~3e-4 << bf16 rounding of the output
static __device__ __forceinline__ float gelu_fast(float v) {
  const float u2 = v * (1.5957691216f + 0.0713548163f * v * v);  // 2*0.7978846*(v+0.044715v^3)
  const float ez = __expf(u2);
  return v * ez / (ez + 1.0f);
}

template<int EPI, int NBX2, int WSEL>
__global__ __launch_bounds__(256, 2)
void gemm2x(const __hip_bfloat16* __restrict__ A, const __hip_bfloat16* __restrict__ Bt,
            const float* __restrict__ bias, __hip_bfloat16* __restrict__ Cout,
            int Nn, int K,
            const int* __restrict__ work, const int* __restrict__ wcnt)
{
  extern __shared__ __align__(16) char lds[];
  const int T = wcnt[WSEL];
  const int bId = blockIdx.x;
  const int cpx = (T + 7) >> 3;
  if ((bId >> 3) >= cpx) return;
  const int idx = (bId & 7) * cpx + (bId >> 3);
  if (idx >= T) return;
  const int p = idx / NBX2;
  const int bx0 = idx % NBX2;
  const int bx = (p & 1) ? (NBX2 - 1 - bx0) : bx0;   // serpentine for L2 reuse
  const int w = work[p];
  const int e = w >> 8, by = w & 255;

  const int t = threadIdx.x, wv = t >> 6, lane = t & 63;
  const int wm = wv >> 1, wn = wv & 1;
  const int fr = lane & 15, fk = lane >> 4;
  const int ntk = K >> 6;

  const __hip_bfloat16* Ae = A + (size_t)e * CAPC * K + (size_t)by * 128 * K;
  const __hip_bfloat16* Be = Bt + (size_t)e * Nn * K + (size_t)bx * 128 * K;

  floatx4 acc[4][4] = {};

  stage_ab(Ae, Be, lds, K, 0, 0, wv, lane);
  stage_ab(Ae, Be, lds, K, 0, 1, wv, lane);
  stage_ab(Ae, Be, lds, K, 1, 0, wv, lane);
  stage_ab(Ae, Be, lds, K, 1, 1, wv, lane);
  SB0();

  for (int kt = 0; kt < ntk - 2; ++kt)
    ktile2<8, true>(kt, lds, Ae, Be, K, acc, wm, wn, fr, fk, wv, lane);
  ktile2<8, false>(ntk - 2, lds, Ae, Be, K, acc, wm, wn, fr, fk, wv, lane);
  ktile2<0, false>(ntk - 1, lds, Ae, Be, K, acc, wm, wn, fr, fk, wv, lane);

  // epilogue: C/D layout col = lane&15, row = (lane>>4)*4 + j.
  // LDS-staged coalesced bf16 stores, wave-private 2KB region (all waves have
  // passed the final K-tile's barriers; K-loop buffers dead).
  const float* be = bias + (size_t)e * Nn;
  unsigned short* Cb = (unsigned short*)Cout + (size_t)e * CAPC * Nn;
  const int m0 = by * 128, n0 = bx * 128;
  unsigned short* ep = (unsigned short*)(lds + wv * 2048);
  float bcol[4];
#pragma unroll
  for (int ni = 0; ni < 4; ++ni) bcol[ni] = be[n0 + wn * 64 + ni * 16 + fr];
#pragma unroll
  for (int mi = 0; mi < 4; ++mi) {
#pragma unroll
    for (int ni = 0; ni < 4; ++ni)
#pragma unroll
      for (int j = 0; j < 4; ++j) {
        float v = acc[mi][ni][j] + bcol[ni];
        if (EPI == 1) v = gelu_fast(v);
        const int row = fk * 4 + j;
        *(unsigned short*)((char*)ep + row * 128 + ((ni * 32 + fr * 2) ^ (fk << 5))) = f2bf(v);
      }
    LGKM(0); SB0();
    const int r = lane & 15;
    const int grow = m0 + wm * 64 + mi * 16 + r;
#pragma unroll
    for (int it = 0; it < 2; ++it) {
      const int q = (lane >> 4) + it * 4;
      const short8 vv = *(const short8*)((char*)ep + r * 128 + ((q * 16) ^ ((r >> 2) << 5)));
      *(short8*)(Cb + (size_t)grow * Nn + n0 + wn * 64 + q * 8) = vv;
    }
    LGKM(0); SB0();
  }
}

// ---------------------------------------------------------------------------
// K7: combine — out[n] = w0*exp_out[e0][s0] + w1*exp_out[e1][s1], bf16 eout.
// ---------------------------------------------------------------------------
__global__ __launch_bounds__(256)
void combine_kernel(const __hip_bfloat16* __restrict__ eout, const int* __restrict__ eidx,
                    const float* __restrict__ pval, const int* __restrict__ slot,
                    float* __restrict__ out)
{
  const int wv = threadIdx.x >> 6, lane = threadIdx.x & 63;
  const int n = blockIdx.x * 4 + wv;
  const int e0 = eidx[n], e1 = eidx[N_TOK + n];
  int s0 = slot[n], s1 = slot[N_TOK + n];
  const float w0 = (s0 >= 0) ? pval[n] : 0.f;
  const float w1 = (s1 >= 0) ? pval[N_TOK + n] : 0.f;
  s0 = (s0 >= 0) ? s0 : 0;
  s1 = (s1 >= 0) ? s1 : 0;
  const ushort4* r0 = (const ushort4*)((const unsigned short*)eout + ((size_t)e0 * CAPC + s0) * CDIM);
  const ushort4* r1 = (const ushort4*)((const unsigned short*)eout + ((size_t)e1 * CAPC + s1) * CDIM);
  float4* o = (float4*)(out + (size_t)n * CDIM);
#pragma unroll
  for (int i = 0; i < 3; ++i) {
    const ushort4 a = r0[i * 64 + lane];
    const ushort4 b = r1[i * 64 + lane];
    float4 c;
    c.x = w0 * bf2f(a.x) + w1 * bf2f(b.x);
    c.y = w0 * bf2f(a.y) + w1 * bf2f(b.y);
    c.z = w0 * bf2f(a.z) + w1 * bf2f(b.z);
    c.w = w0 * bf2f(a.w) + w1 * bf2f(b.w);
    o[i * 64 + lane] = c;
  }
}

// ---------------------------------------------------------------------------
extern "C" void kernel_launch(void* const* d_in, const int* in_sizes, int n_in,
                              void* d_out, int out_size, void* d_ws, size_t ws_size,
                              hipStream_t stream)
{
  const float* x   = (const float*)d_in[0];
  const float* wg  = (const float*)d_in[1];
  const float* cfc = (const float*)d_in[2];
  const float* fcb = (const float*)d_in[3];
  const float* cpr = (const float*)d_in[4];
  const float* prb = (const float*)d_in[5];
  float* out = (float*)d_out;

  char* ws = (char*)d_ws;
  size_t off = 0;
  auto take = [&](size_t bytes) -> void* {
    void* p = ws + off;
    off += (bytes + 255) & ~(size_t)255;
    return p;
  };
  __hip_bfloat16* wfcT = (__hip_bfloat16*)take((size_t)E_EXP * HDIM * CDIM * 2); // [E][3072][768]
  __hip_bfloat16* wprT = (__hip_bfloat16*)take((size_t)E_EXP * CDIM * HDIM * 2); // [E][768][3072]
  __hip_bfloat16* xin  = (__hip_bfloat16*)take((size_t)E_EXP * CAPC * CDIM * 2); // [E][CAP][768]
  __hip_bfloat16* hbuf = (__hip_bfloat16*)take((size_t)E_EXP * CAPC * HDIM * 2); // [E][CAP][3072]
  __hip_bfloat16* eout = (__hip_bfloat16*)take((size_t)E_EXP * CAPC * CDIM * 2); // [E][CAP][768] bf16
  int*   eidx = (int*)take((size_t)2 * N_TOK * 4);
  float* pv   = (float*)take((size_t)2 * N_TOK * 4);
  int*   slot = (int*)take((size_t)2 * N_TOK * 4);
  int*   stok = (int*)take((size_t)E_EXP * CAPC * 4);
  int*   ecnt = (int*)take((size_t)E_EXP * 4);
  int*   work2 = (int*)take((size_t)128 * 4);
  int*   wcnt = (int*)take((size_t)2 * 4);

  hipFuncSetAttribute((const void*)gemm2x<1, 24, 0>,
                      hipFuncAttributeMaxDynamicSharedMemorySize, 65536);
  hipFuncSetAttribute((const void*)gemm2x<2, 6, 1>,
                      hipFuncAttributeMaxDynamicSharedMemorySize, 65536);

  // weight transpose+convert (64x64 tiles)
  transpose64<<<dim3(HDIM / 64, CDIM / 64, E_EXP), 256, 0, stream>>>(cfc, wfcT, CDIM, HDIM);
  transpose64<<<dim3(CDIM / 64, HDIM / 64, E_EXP), 256, 0, stream>>>(cpr, wprT, HDIM, CDIM);

  router_kernel<<<N_TOK / 4, 256, 0, stream>>>(x, wg, eidx, pv);
  scan_kernel<<<1, 256, 0, stream>>>(eidx, slot, stok, ecnt, work2, wcnt);
  dispatch_kernel<<<(E_EXP * CAPC) / 4, 256, 0, stream>>>(x, stok, ecnt, xin);

  // GEMM1 + bias + GELU -> h (bf16): active 128-row tiles, Nn=3072, K=768,
  // 24 n-tiles/pair; grid = worst-case 3072 items, 2 blocks/CU.
  gemm2x<1, 24, 0><<<3072, 256, 65536, stream>>>(xin, wfcT, fcb, hbuf, HDIM, CDIM, work2, wcnt);
  // GEMM2 + bias -> eout (bf16): same tile pairs, Nn=768, K=3072, 6 n-tiles.
  gemm2x<2, 6, 1><<<768, 256, 65536, stream>>>(hbuf, wprT, prb, eout, CDIM, HDIM, work2, wcnt);

  combine_kernel<<<N_TOK / 4, 256, 0, stream>>>(eout, eidx, pv, slot, out);
}

// Round 11
// 175.362 us; speedup vs baseline: 2.3824x; 1.0603x over previous
//
#include <hip/hip_runtime.h>
#include <hip/hip_bf16.h>
#include <math.h>

// Problem constants (B=4, T=1024, C=768, E=8, K=2)
#define N_TOK 4096
#define CDIM  768
#define E_EXP 8
#define CAPC  2048
#define HDIM  3072   // 4*C

typedef __attribute__((ext_vector_type(8))) short short8;
typedef __attribute__((ext_vector_type(4))) float floatx4;

#define VMCNT(n) asm volatile("s_waitcnt vmcnt(" #n ")" ::: "memory")
#define LGKM(n)  asm volatile("s_waitcnt lgkmcnt(" #n ")" ::: "memory")
#define SB0()    __builtin_amdgcn_sched_barrier(0)

static __device__ __forceinline__ unsigned short f2bf(float f) {
  __hip_bfloat16 h = __float2bfloat16(f);
  return __builtin_bit_cast(unsigned short, h);
}
static __device__ __forceinline__ float bf2f(unsigned short u) {
  return __builtin_bit_cast(float, (unsigned int)u << 16);
}

// ---------------------------------------------------------------------------
// K1: fused prep — both weight transposes (64x64 tiles, f32->bf16) + router.
// blockIdx partition: [0,4608) c_fc transpose; [4608,9216) c_proj transpose;
// [9216,10240) router.  All jobs independent.
// ---------------------------------------------------------------------------
__device__ __forceinline__ void transpose_body(const float* __restrict__ ie,
                                               unsigned short* __restrict__ oe,
                                               int R, int Cc, int c0, int r0,
                                               float (*tile)[65])
{
  const int t = threadIdx.x;
  {
    const int r = t >> 2, c = (t & 3) * 4;
#pragma unroll
    for (int i = 0; i < 4; ++i) {
      const float4 v = *(const float4*)(ie + (size_t)(r0 + r) * Cc + c0 + c + i * 16);
      tile[r][c + i * 16 + 0] = v.x; tile[r][c + i * 16 + 1] = v.y;
      tile[r][c + i * 16 + 2] = v.z; tile[r][c + i * 16 + 3] = v.w;
    }
  }
  __syncthreads();
  {
    const int cc = t >> 2, rq = (t & 3) * 16;
    unsigned short o[16];
#pragma unroll
    for (int i = 0; i < 16; ++i) o[i] = f2bf(tile[rq + i][cc]);
    unsigned short* dst = oe + (size_t)(c0 + cc) * R + r0 + rq;
    *(short8*)(dst)     = *(short8*)&o[0];
    *(short8*)(dst + 8) = *(short8*)&o[8];
  }
}

__global__ __launch_bounds__(256)
void prep_kernel(const float* __restrict__ cfc, const float* __restrict__ cpr,
                 __hip_bfloat16* __restrict__ wfcT, __hip_bfloat16* __restrict__ wprT,
                 const float* __restrict__ x, const float* __restrict__ wg,
                 int* __restrict__ eidx, float* __restrict__ pval)
{
  __shared__ float tile[64][65];
  const int b = blockIdx.x;
  if (b < 4608) {
    // c_fc [E][768][3072] -> wfcT [E][3072][768]; grid (48 x, 12 y, 8 e)
    const int e = b / (48 * 12), rem = b % (48 * 12);
    const int c0 = (rem % 48) * 64, r0 = (rem / 48) * 64;
    transpose_body(cfc + (size_t)e * CDIM * HDIM,
                   (unsigned short*)wfcT + (size_t)e * HDIM * CDIM,
                   CDIM, HDIM, c0, r0, tile);
  } else if (b < 9216) {
    // c_proj [E][3072][768] -> wprT [E][768][3072]; grid (12 x, 48 y, 8 e)
    const int bb = b - 4608;
    const int e = bb / (12 * 48), rem = bb % (12 * 48);
    const int c0 = (rem % 12) * 64, r0 = (rem / 12) * 64;
    transpose_body(cpr + (size_t)e * HDIM * CDIM,
                   (unsigned short*)wprT + (size_t)e * CDIM * HDIM,
                   HDIM, CDIM, c0, r0, tile);
  } else {
    // router: one wave per token
    const int wv = threadIdx.x >> 6, lane = threadIdx.x & 63;
    const int n = (b - 9216) * 4 + wv;
    const float* xr = x + (size_t)n * CDIM;
    float acc[E_EXP] = {0.f, 0.f, 0.f, 0.f, 0.f, 0.f, 0.f, 0.f};
#pragma unroll
    for (int i = 0; i < CDIM / 64; ++i) {
      const float xv = xr[i * 64 + lane];
#pragma unroll
      for (int e = 0; e < E_EXP; ++e)
        acc[e] = fmaf(xv, wg[e * CDIM + i * 64 + lane], acc[e]);
    }
#pragma unroll
    for (int e = 0; e < E_EXP; ++e) {
#pragma unroll
      for (int off = 32; off > 0; off >>= 1)
        acc[e] += __shfl_xor(acc[e], off);
    }
    if (lane == 0) {
      int e0 = 0; float v0 = acc[0];
#pragma unroll
      for (int e = 1; e < E_EXP; ++e) if (acc[e] > v0) { v0 = acc[e]; e0 = e; }
      int e1 = -1; float v1 = -3.4e38f;
#pragma unroll
      for (int e = 0; e < E_EXP; ++e) if (e != e0 && acc[e] > v1) { v1 = acc[e]; e1 = e; }
      const float ex = __expf(v1 - v0);
      const float inv = 1.f / (1.f + ex);
      eidx[n] = e0; eidx[N_TOK + n] = e1;
      pval[n] = inv; pval[N_TOK + n] = ex * inv;
    }
  }
}

// ---------------------------------------------------------------------------
// K4: capacity scan (k-major reference order), single block Hillis-Steele.
// Emits ecnt[e] and a compact 128-row-tile work list shared by both GEMMs:
//   work2: (e<<8|by128);  wcnt[0] = npairs*24 (gemm1), wcnt[1] = npairs*6.
// ---------------------------------------------------------------------------
__global__ __launch_bounds__(256)
void scan_kernel(const int* __restrict__ eidx, int* __restrict__ slot,
                 int* __restrict__ slot_token, int* __restrict__ ecnt,
                 int* __restrict__ work2, int* __restrict__ wcnt)
{
  const int t = threadIdx.x;
  const int base = t * 32;
  int e_local[32];
  int cnt[E_EXP] = {0, 0, 0, 0, 0, 0, 0, 0};
#pragma unroll
  for (int i = 0; i < 32; ++i) {
    const int e = eidx[base + i];
    e_local[i] = e;
    cnt[e]++;
  }
  __shared__ int hist[256][E_EXP];
  __shared__ int secnt[E_EXP];
#pragma unroll
  for (int e = 0; e < E_EXP; ++e) hist[t][e] = cnt[e];
  __syncthreads();
  for (int off = 1; off < 256; off <<= 1) {
    int v[E_EXP] = {0, 0, 0, 0, 0, 0, 0, 0};
    if (t >= off) {
#pragma unroll
      for (int e = 0; e < E_EXP; ++e) v[e] = hist[t - off][e];
    }
    __syncthreads();
    if (t >= off) {
#pragma unroll
      for (int e = 0; e < E_EXP; ++e) hist[t][e] += v[e];
    }
    __syncthreads();
  }
  if (t == 255) {
#pragma unroll
    for (int e = 0; e < E_EXP; ++e) {
      const int tot = hist[255][e];
      const int c = tot < CAPC ? tot : CAPC;
      ecnt[e] = c;
      secnt[e] = c;
    }
  }
  __syncthreads();
  if (t == 0) {
    int n2 = 0;
    for (int e = 0; e < E_EXP; ++e) {
      const int c = secnt[e];
      const int t2 = (c + 127) >> 7;
      for (int b = 0; b < t2; ++b) work2[n2++] = (e << 8) | b;
    }
    wcnt[0] = n2 * 24;
    wcnt[1] = n2 * 6;
  }
  int run[E_EXP];
#pragma unroll
  for (int e = 0; e < E_EXP; ++e) run[e] = hist[t][e] - cnt[e];
#pragma unroll
  for (int i = 0; i < 32; ++i) {
    const int a = base + i;
    const int e = e_local[i];
    const int r = run[e]++;
    const int s = (r < CAPC) ? r : -1;
    slot[a] = s;
    if (s >= 0) slot_token[e * CAPC + s] = (a < N_TOK) ? a : (a - N_TOK);
  }
}

// ---------------------------------------------------------------------------
// K5: dispatch — exp_in row = bf16(x[token]) for used slots only.
// ---------------------------------------------------------------------------
__global__ __launch_bounds__(256)
void dispatch_kernel(const float* __restrict__ x, const int* __restrict__ slot_token,
                     const int* __restrict__ ecnt, __hip_bfloat16* __restrict__ xin)
{
  const int wv = threadIdx.x >> 6, lane = threadIdx.x & 63;
  const int s = blockIdx.x * 4 + wv;
  const int e = s >> 11;                 // CAPC = 2048
  if ((s & (CAPC - 1)) >= ecnt[e]) return;
  const int n = slot_token[s];
  unsigned short* orow = (unsigned short*)xin + (size_t)s * CDIM;
  const float4* xr = (const float4*)(x + (size_t)n * CDIM);
#pragma unroll
  for (int i = 0; i < 3; ++i) {
    const float4 v = xr[i * 64 + lane];
    ushort4 o;
    o.x = f2bf(v.x); o.y = f2bf(v.y); o.z = f2bf(v.z); o.w = f2bf(v.w);
    *(ushort4*)(orow + (size_t)(i * 64 + lane) * 4) = o;
  }
}

// ---------------------------------------------------------------------------
// K6 core: 128x128-tile GEMM body, BK=64, 4 waves (2Mx2N), dbuf 64 KiB,
// counted vmcnt + counted LGKM (proven round-5/9/10 body).
// ---------------------------------------------------------------------------
__device__ __forceinline__ void stage_ab(const __hip_bfloat16* Ae, const __hip_bfloat16* Be,
                                         char* lds, int K, int kt, int isB,
                                         int wv, int lane)
{
  const char* src = (const char*)(isB ? Be : Ae);
  char* dst = lds + (kt & 1) * 32768 + isB * 16384;
#pragma unroll
  for (int j = 0; j < 4; ++j) {
    const int li = j * 32 + wv * 8 + (lane >> 3);
    const int kb = ((lane & 7) * 16) ^ ((li & 7) << 4);  // pre-swizzled source
    const char* g = src + ((size_t)li * K + (size_t)kt * 64) * 2 + kb;
    char* lp = dst + j * 4096 + wv * 1024;
    __builtin_amdgcn_global_load_lds((const __attribute__((address_space(1))) unsigned int*)g,
                                     (__attribute__((address_space(3))) unsigned int*)lp, 16, 0, 0);
  }
}

template<int VME, bool S2>
__device__ __forceinline__ void ktile2(int kt, char* lds,
                                       const __hip_bfloat16* Ae, const __hip_bfloat16* Be,
                                       int K, floatx4 (&acc)[4][4],
                                       int wm, int wn, int fr, int fk, int wv, int lane)
{
  if constexpr (VME == 8) VMCNT(8); else VMCNT(0);
  __builtin_amdgcn_s_barrier();
  SB0();
  const char* bufA = lds + ((kt & 1) ? 32768 : 0);
  const char* bufB = bufA + 16384;
  short8 a[4][2], b[4][2];
#pragma unroll
  for (int mi = 0; mi < 4; ++mi) {
    const int lr = wm * 64 + mi * 16 + fr;
    a[mi][0] = *(const short8*)(bufA + lr * 128 + ((fk * 16) ^ ((lr & 7) << 4)));
  }
#pragma unroll
  for (int ni = 0; ni < 4; ++ni) {
    const int lj = wn * 64 + ni * 16 + fr;
    b[ni][0] = *(const short8*)(bufB + lj * 128 + ((fk * 16) ^ ((lj & 7) << 4)));
  }
  SB0();
#pragma unroll
  for (int mi = 0; mi < 4; ++mi) {
    const int lr = wm * 64 + mi * 16 + fr;
    a[mi][1] = *(const short8*)(bufA + lr * 128 + ((64 + fk * 16) ^ ((lr & 7) << 4)));
  }
#pragma unroll
  for (int ni = 0; ni < 4; ++ni) {
    const int lj = wn * 64 + ni * 16 + fr;
    b[ni][1] = *(const short8*)(bufB + lj * 128 + ((64 + fk * 16) ^ ((lj & 7) << 4)));
  }
  SB0();
  LGKM(8); SB0();
  __builtin_amdgcn_s_setprio(1);
#pragma unroll
  for (int mi = 0; mi < 4; ++mi)
#pragma unroll
    for (int ni = 0; ni < 4; ++ni)
      acc[mi][ni] = __builtin_amdgcn_mfma_f32_16x16x32_bf16(a[mi][0], b[ni][0], acc[mi][ni], 0, 0, 0);
  __builtin_amdgcn_s_setprio(0);
  SB0();
  LGKM(0); SB0();
  __builtin_amdgcn_s_setprio(1);
#pragma unroll
  for (int mi = 0; mi < 4; ++mi)
#pragma unroll
    for (int ni = 0; ni < 4; ++ni)
      acc[mi][ni] = __builtin_amdgcn_mfma_f32_16x16x32_bf16(a[mi][1], b[ni][1], acc[mi][ni], 0, 0, 0);
  __builtin_amdgcn_s_setprio(0);
  SB0();
  __builtin_amdgcn_s_barrier();
  if (S2) {
    stage_ab(Ae, Be, lds, K, kt + 2, 0, wv, lane);
    stage_ab(Ae, Be, lds, K, kt + 2, 1, wv, lane);
  }
  SB0();
}

// fast exact-grade GELU: tanh form, |err| ~3e-4 << bf16 rounding of the output
static __device__ __forceinline__ float gelu_fast(float v) {
  const float u2 = v * (1.5957691216f + 0.0713548163f * v * v);
  const float ez = __expf(u2);
  return v * ez / (ez + 1.0f);
}

// Shared epilogue: LDS-staged coalesced bf16 store (wave-private 2KB region).
template<int EPI>
__device__ __forceinline__ void epilogue_bf16(floatx4 (&acc)[4][4], char* lds,
                                              const float* be, unsigned short* Cb,
                                              int Nn, int m0, int n0,
                                              int wm, int wn, int fr, int fk,
                                              int wv, int lane)
{
  unsigned short* ep = (unsigned short*)(lds + wv * 2048);
  float bcol[4];
#pragma unroll
  for (int ni = 0; ni < 4; ++ni) bcol[ni] = be[n0 + wn * 64 + ni * 16 + fr];
#pragma unroll
  for (int mi = 0; mi < 4; ++mi) {
#pragma unroll
    for (int ni = 0; ni < 4; ++ni)
#pragma unroll
      for (int j = 0; j < 4; ++j) {
        float v = acc[mi][ni][j] + bcol[ni];
        if (EPI == 1) v = gelu_fast(v);
        const int row = fk * 4 + j;
        *(unsigned short*)((char*)ep + row * 128 + ((ni * 32 + fr * 2) ^ (fk << 5))) = f2bf(v);
      }
    LGKM(0); SB0();
    const int r = lane & 15;
    const int grow = m0 + wm * 64 + mi * 16 + r;
#pragma unroll
    for (int it = 0; it < 2; ++it) {
      const int q = (lane >> 4) + it * 4;
      const short8 vv = *(const short8*)((char*)ep + r * 128 + ((q * 16) ^ ((r >> 2) << 5)));
      *(short8*)(Cb + (size_t)grow * Nn + n0 + wn * 64 + q * 8) = vv;
    }
    LGKM(0); SB0();
  }
}

// ---------------------------------------------------------------------------
// K6a: GEMM1 persistent — grid 512 (2 blocks/CU, all resident); each block
// loops over its XCD-chunked share of the work list (stride 64 within chunk).
// Item i+1's prologue overlaps item i's epilogue; one barrier guards LDS reuse.
// ---------------------------------------------------------------------------
__global__ __launch_bounds__(256, 2)
void gemm1p(const __hip_bfloat16* __restrict__ A, const __hip_bfloat16* __restrict__ Bt,
            const float* __restrict__ bias, __hip_bfloat16* __restrict__ Cout,
            const int* __restrict__ work, const int* __restrict__ wcnt)
{
  extern __shared__ __align__(16) char lds[];
  const int T = wcnt[0];
  const int cpx = (T + 7) >> 3;
  const int x8 = blockIdx.x & 7, l = blockIdx.x >> 3;   // XCD id, local slot (0..63)
  const int lim = (x8 + 1) * cpx < T ? (x8 + 1) * cpx : T;

  const int t = threadIdx.x, wv = t >> 6, lane = t & 63;
  const int wm = wv >> 1, wn = wv & 1;
  const int fr = lane & 15, fk = lane >> 4;
  constexpr int ntk = CDIM / 64;   // 12

  for (int i = x8 * cpx + l; i < lim; i += 64) {
    const int p = i / 24;
    const int bx0 = i % 24;
    const int bx = (p & 1) ? (23 - bx0) : bx0;          // serpentine for L2 reuse
    const int w = work[p];
    const int e = w >> 8, by = w & 255;

    const __hip_bfloat16* Ae = A + (size_t)e * CAPC * CDIM + (size_t)by * 128 * CDIM;
    const __hip_bfloat16* Be = Bt + (size_t)e * HDIM * CDIM + (size_t)bx * 128 * CDIM;

    floatx4 acc[4][4] = {};

    stage_ab(Ae, Be, lds, CDIM, 0, 0, wv, lane);
    stage_ab(Ae, Be, lds, CDIM, 0, 1, wv, lane);
    stage_ab(Ae, Be, lds, CDIM, 1, 0, wv, lane);
    stage_ab(Ae, Be, lds, CDIM, 1, 1, wv, lane);
    SB0();

#pragma unroll 1
    for (int kt = 0; kt < ntk - 2; ++kt)
      ktile2<8, true>(kt, lds, Ae, Be, CDIM, acc, wm, wn, fr, fk, wv, lane);
    ktile2<8, false>(ntk - 2, lds, Ae, Be, CDIM, acc, wm, wn, fr, fk, wv, lane);
    ktile2<0, false>(ntk - 1, lds, Ae, Be, CDIM, acc, wm, wn, fr, fk, wv, lane);

    epilogue_bf16<1>(acc, lds,
                     bias + (size_t)e * HDIM,
                     (unsigned short*)Cout + (size_t)e * CAPC * HDIM,
                     HDIM, by * 128, bx * 128, wm, wn, fr, fk, wv, lane);
    __builtin_amdgcn_s_barrier();   // all waves done with LDS epilogue regions
    SB0();
  }
}

// ---------------------------------------------------------------------------
// K6b: GEMM2 — single round (<=768 blocks, 2/CU), round-10 body.
// ---------------------------------------------------------------------------
__global__ __launch_bounds__(256, 2)
void gemm2x(const __hip_bfloat16* __restrict__ A, const __hip_bfloat16* __restrict__ Bt,
            const float* __restrict__ bias, __hip_bfloat16* __restrict__ Cout,
            const int* __restrict__ work, const int* __restrict__ wcnt)
{
  extern __shared__ __align__(16) char lds[];
  const int T = wcnt[1];
  const int bId = blockIdx.x;
  const int cpx = (T + 7) >> 3;
  if ((bId >> 3) >= cpx) return;
  const int idx = (bId & 7) * cpx + (bId >> 3);
  if (idx >= T) return;
  const int p = idx / 6;
  const int bx0 = idx % 6;
  const int bx = (p & 1) ? (5 - bx0) : bx0;
  const int w = work[p];
  const int e = w >> 8, by = w & 255;

  const int t = threadIdx.x, wv = t >> 6, lane = t & 63;
  const int wm = wv >> 1, wn = wv & 1;
  const int fr = lane & 15, fk = lane >> 4;
  constexpr int ntk = HDIM / 64;   // 48

  const __hip_bfloat16* Ae = A + (size_t)e * CAPC * HDIM + (size_t)by * 128 * HDIM;
  const __hip_bfloat16* Be = Bt + (size_t)e * CDIM * HDIM + (size_t)bx * 128 * HDIM;

  floatx4 acc[4][4] = {};

  stage_ab(Ae, Be, lds, HDIM, 0, 0, wv, lane);
  stage_ab(Ae, Be, lds, HDIM, 0, 1, wv, lane);
  stage_ab(Ae, Be, lds, HDIM, 1, 0, wv, lane);
  stage_ab(Ae, Be, lds, HDIM, 1, 1, wv, lane);
  SB0();

#pragma unroll 1
  for (int kt = 0; kt < ntk - 2; ++kt)
    ktile2<8, true>(kt, lds, Ae, Be, HDIM, acc, wm, wn, fr, fk, wv, lane);
  ktile2<8, false>(ntk - 2, lds, Ae, Be, HDIM, acc, wm, wn, fr, fk, wv, lane);
  ktile2<0, false>(ntk - 1, lds, Ae, Be, HDIM, acc, wm, wn, fr, fk, wv, lane);

  epilogue_bf16<2>(acc, lds,
                   bias + (size_t)e * CDIM,
                   (unsigned short*)Cout + (size_t)e * CAPC * CDIM,
                   CDIM, by * 128, bx * 128, wm, wn, fr, fk, wv, lane);
}

// ---------------------------------------------------------------------------
// K7: combine — out[n] = w0*exp_out[e0][s0] + w1*exp_out[e1][s1], bf16 eout.
// ---------------------------------------------------------------------------
__global__ __launch_bounds__(256)
void combine_kernel(const __hip_bfloat16* __restrict__ eout, const int* __restrict__ eidx,
                    const float* __restrict__ pval, const int* __restrict__ slot,
                    float* __restrict__ out)
{
  const int wv = threadIdx.x >> 6, lane = threadIdx.x & 63;
  const int n = blockIdx.x * 4 + wv;
  const int e0 = eidx[n], e1 = eidx[N_TOK + n];
  int s0 = slot[n], s1 = slot[N_TOK + n];
  const float w0 = (s0 >= 0) ? pval[n] : 0.f;
  const float w1 = (s1 >= 0) ? pval[N_TOK + n] : 0.f;
  s0 = (s0 >= 0) ? s0 : 0;
  s1 = (s1 >= 0) ? s1 : 0;
  const ushort4* r0 = (const ushort4*)((const unsigned short*)eout + ((size_t)e0 * CAPC + s0) * CDIM);
  const ushort4* r1 = (const ushort4*)((const unsigned short*)eout + ((size_t)e1 * CAPC + s1) * CDIM);
  float4* o = (float4*)(out + (size_t)n * CDIM);
#pragma unroll
  for (int i = 0; i < 3; ++i) {
    const ushort4 a = r0[i * 64 + lane];
    const ushort4 b = r1[i * 64 + lane];
    float4 c;
    c.x = w0 * bf2f(a.x) + w1 * bf2f(b.x);
    c.y = w0 * bf2f(a.y) + w1 * bf2f(b.y);
    c.z = w0 * bf2f(a.z) + w1 * bf2f(b.z);
    c.w = w0 * bf2f(a.w) + w1 * bf2f(b.w);
    o[i * 64 + lane] = c;
  }
}

// ---------------------------------------------------------------------------
extern "C" void kernel_launch(void* const* d_in, const int* in_sizes, int n_in,
                              void* d_out, int out_size, void* d_ws, size_t ws_size,
                              hipStream_t stream)
{
  const float* x   = (const float*)d_in[0];
  const float* wg  = (const float*)d_in[1];
  const float* cfc = (const float*)d_in[2];
  const float* fcb = (const float*)d_in[3];
  const float* cpr = (const float*)d_in[4];
  const float* prb = (const float*)d_in[5];
  float* out = (float*)d_out;

  char* ws = (char*)d_ws;
  size_t off = 0;
  auto take = [&](size_t bytes) -> void* {
    void* p = ws + off;
    off += (bytes + 255) & ~(size_t)255;
    return p;
  };
  __hip_bfloat16* wfcT = (__hip_bfloat16*)take((size_t)E_EXP * HDIM * CDIM * 2); // [E][3072][768]
  __hip_bfloat16* wprT = (__hip_bfloat16*)take((size_t)E_EXP * CDIM * HDIM * 2); // [E][768][3072]
  __hip_bfloat16* xin  = (__hip_bfloat16*)take((size_t)E_EXP * CAPC * CDIM * 2); // [E][CAP][768]
  __hip_bfloat16* hbuf = (__hip_bfloat16*)take((size_t)E_EXP * CAPC * HDIM * 2); // [E][CAP][3072]
  __hip_bfloat16* eout = (__hip_bfloat16*)take((size_t)E_EXP * CAPC * CDIM * 2); // [E][CAP][768] bf16
  int*   eidx = (int*)take((size_t)2 * N_TOK * 4);
  float* pv   = (float*)take((size_t)2 * N_TOK * 4);
  int*   slot = (int*)take((size_t)2 * N_TOK * 4);
  int*   stok = (int*)take((size_t)E_EXP * CAPC * 4);
  int*   ecnt = (int*)take((size_t)E_EXP * 4);
  int*   work2 = (int*)take((size_t)128 * 4);
  int*   wcnt = (int*)take((size_t)2 * 4);

  hipFuncSetAttribute((const void*)gemm1p,
                      hipFuncAttributeMaxDynamicSharedMemorySize, 65536);
  hipFuncSetAttribute((const void*)gemm2x,
                      hipFuncAttributeMaxDynamicSharedMemorySize, 65536);

  // fused prep: both weight transposes + router (independent jobs)
  prep_kernel<<<4608 + 4608 + 1024, 256, 0, stream>>>(cfc, cpr, wfcT, wprT,
                                                      x, wg, eidx, pv);
  scan_kernel<<<1, 256, 0, stream>>>(eidx, slot, stok, ecnt, work2, wcnt);
  dispatch_kernel<<<(E_EXP * CAPC) / 4, 256, 0, stream>>>(x, stok, ecnt, xin);

  // GEMM1 + bias + GELU -> h (bf16): persistent 512 blocks (2/CU), work-looped.
  gemm1p<<<512, 256, 65536, stream>>>(xin, wfcT, fcb, hbuf, work2, wcnt);
  // GEMM2 + bias -> eout (bf16): single round, <=768 active blocks.
  gemm2x<<<768, 256, 65536, stream>>>(hbuf, wprT, prb, eout, work2, wcnt);

  combine_kernel<<<N_TOK / 4, 256, 0, stream>>>(eout, eidx, pv, slot, out);
}

// Round 12
// 169.021 us; speedup vs baseline: 2.4718x; 1.0375x over previous
//
#include <hip/hip_runtime.h>
#include <hip/hip_bf16.h>
#include <math.h>

// Problem constants (B=4, T=1024, C=768, E=8, K=2)
#define N_TOK 4096
#define CDIM  768
#define E_EXP 8
#define CAPC  2048
#define HDIM  3072   // 4*C

typedef __attribute__((ext_vector_type(8))) short short8;
typedef __attribute__((ext_vector_type(4))) float floatx4;

#define VMCNT(n) asm volatile("s_waitcnt vmcnt(" #n ")" ::: "memory")
#define LGKM(n)  asm volatile("s_waitcnt lgkmcnt(" #n ")" ::: "memory")
#define SB0()    __builtin_amdgcn_sched_barrier(0)

static __device__ __forceinline__ unsigned short f2bf(float f) {
  __hip_bfloat16 h = __float2bfloat16(f);
  return __builtin_bit_cast(unsigned short, h);
}
static __device__ __forceinline__ float bf2f(unsigned short u) {
  return __builtin_bit_cast(float, (unsigned int)u << 16);
}

// ---------------------------------------------------------------------------
// K1: fused prep — weight transposes into TILED bf16 layout + router.
// Tiled layout: W^T stored as [e][bx][kt][128 n][64 k] 16KB tiles, so the
// transpose writes 16KB contiguous per block (2KB/wave) and the GEMM stage
// reads  tile_base + kt*16384 + li*128 + kb  (same LDS image as before).
// blockIdx partition: [0,2304) c_fc; [2304,4608) c_proj; [4608,5632) router.
// ---------------------------------------------------------------------------
__global__ __launch_bounds__(256)
void prep_kernel(const float* __restrict__ cfc, const float* __restrict__ cpr,
                 __hip_bfloat16* __restrict__ wfcT, __hip_bfloat16* __restrict__ wprT,
                 const float* __restrict__ x, const float* __restrict__ wg,
                 int* __restrict__ eidx, float* __restrict__ pval)
{
  __shared__ float tile[64][129];   // [k][n] f32, pad->129 (2-way col reads)
  const int b = blockIdx.x;
  const int t = threadIdx.x;
  if (b < 4608) {
    const float* src;
    unsigned short* dstT;
    int Cc, bx, kt;
    if (b < 2304) {
      // c_fc [E][768][3072]: e,bx<24,kt<12
      const int e = b / 288, rem = b % 288;
      bx = rem % 24; kt = rem / 24;
      src = cfc + (size_t)e * CDIM * HDIM;
      Cc = HDIM;
      dstT = (unsigned short*)wfcT + ((((size_t)e * 24 + bx) * 12) + kt) * 8192;
    } else {
      // c_proj [E][3072][768]: e,bx<6,kt<48
      const int bb = b - 2304;
      const int e = bb / 288, rem = bb % 288;
      bx = rem % 6; kt = rem / 6;
      src = cpr + (size_t)e * HDIM * CDIM;
      Cc = CDIM;
      dstT = (unsigned short*)wprT + ((((size_t)e * 6 + bx) * 48) + kt) * 8192;
    }
    // phase 1: read 64 k-rows x 128 n-cols; 512B full-line segments per row
    const float* sbase = src + (size_t)(kt * 64) * Cc + bx * 128;
#pragma unroll
    for (int i = 0; i < 8; ++i) {
      const int r = i * 8 + (t >> 5);
      const int c = (t & 31) * 4;
      const float4 v = *(const float4*)(sbase + (size_t)r * Cc + c);
      tile[r][c + 0] = v.x; tile[r][c + 1] = v.y;
      tile[r][c + 2] = v.z; tile[r][c + 3] = v.w;
    }
    __syncthreads();
    // phase 2: emit [128 n][64 k] bf16, fully contiguous (2KB per wave)
#pragma unroll
    for (int j = 0; j < 2; ++j) {
      const int n = j * 64 + (t >> 2);
      const int kq = (t & 3) * 16;
      unsigned short o[16];
#pragma unroll
      for (int i = 0; i < 16; ++i) o[i] = f2bf(tile[kq + i][n]);
      unsigned short* d = dstT + n * 64 + kq;
      *(short8*)(d)     = *(short8*)&o[0];
      *(short8*)(d + 8) = *(short8*)&o[8];
    }
  } else {
    // router: one wave per token
    const int wv = t >> 6, lane = t & 63;
    const int n = (b - 4608) * 4 + wv;
    const float* xr = x + (size_t)n * CDIM;
    float acc[E_EXP] = {0.f, 0.f, 0.f, 0.f, 0.f, 0.f, 0.f, 0.f};
#pragma unroll
    for (int i = 0; i < CDIM / 64; ++i) {
      const float xv = xr[i * 64 + lane];
#pragma unroll
      for (int e = 0; e < E_EXP; ++e)
        acc[e] = fmaf(xv, wg[e * CDIM + i * 64 + lane], acc[e]);
    }
#pragma unroll
    for (int e = 0; e < E_EXP; ++e) {
#pragma unroll
      for (int off = 32; off > 0; off >>= 1)
        acc[e] += __shfl_xor(acc[e], off);
    }
    if (lane == 0) {
      int e0 = 0; float v0 = acc[0];
#pragma unroll
      for (int e = 1; e < E_EXP; ++e) if (acc[e] > v0) { v0 = acc[e]; e0 = e; }
      int e1 = -1; float v1 = -3.4e38f;
#pragma unroll
      for (int e = 0; e < E_EXP; ++e) if (e != e0 && acc[e] > v1) { v1 = acc[e]; e1 = e; }
      const float ex = __expf(v1 - v0);
      const float inv = 1.f / (1.f + ex);
      eidx[n] = e0; eidx[N_TOK + n] = e1;
      pval[n] = inv; pval[N_TOK + n] = ex * inv;
    }
  }
}

// ---------------------------------------------------------------------------
// K4: capacity scan (k-major reference order), single block Hillis-Steele.
// Emits ecnt[e] and a compact 128-row-tile work list shared by both GEMMs.
// ---------------------------------------------------------------------------
__global__ __launch_bounds__(256)
void scan_kernel(const int* __restrict__ eidx, int* __restrict__ slot,
                 int* __restrict__ slot_token, int* __restrict__ ecnt,
                 int* __restrict__ work2, int* __restrict__ wcnt)
{
  const int t = threadIdx.x;
  const int base = t * 32;
  int e_local[32];
  int cnt[E_EXP] = {0, 0, 0, 0, 0, 0, 0, 0};
#pragma unroll
  for (int i = 0; i < 32; ++i) {
    const int e = eidx[base + i];
    e_local[i] = e;
    cnt[e]++;
  }
  __shared__ int hist[256][E_EXP];
  __shared__ int secnt[E_EXP];
#pragma unroll
  for (int e = 0; e < E_EXP; ++e) hist[t][e] = cnt[e];
  __syncthreads();
  for (int off = 1; off < 256; off <<= 1) {
    int v[E_EXP] = {0, 0, 0, 0, 0, 0, 0, 0};
    if (t >= off) {
#pragma unroll
      for (int e = 0; e < E_EXP; ++e) v[e] = hist[t - off][e];
    }
    __syncthreads();
    if (t >= off) {
#pragma unroll
      for (int e = 0; e < E_EXP; ++e) hist[t][e] += v[e];
    }
    __syncthreads();
  }
  if (t == 255) {
#pragma unroll
    for (int e = 0; e < E_EXP; ++e) {
      const int tot = hist[255][e];
      const int c = tot < CAPC ? tot : CAPC;
      ecnt[e] = c;
      secnt[e] = c;
    }
  }
  __syncthreads();
  if (t == 0) {
    int n2 = 0;
    for (int e = 0; e < E_EXP; ++e) {
      const int c = secnt[e];
      const int t2 = (c + 127) >> 7;
      for (int b = 0; b < t2; ++b) work2[n2++] = (e << 8) | b;
    }
    wcnt[0] = n2 * 24;
    wcnt[1] = n2 * 6;
  }
  int run[E_EXP];
#pragma unroll
  for (int e = 0; e < E_EXP; ++e) run[e] = hist[t][e] - cnt[e];
#pragma unroll
  for (int i = 0; i < 32; ++i) {
    const int a = base + i;
    const int e = e_local[i];
    const int r = run[e]++;
    const int s = (r < CAPC) ? r : -1;
    slot[a] = s;
    if (s >= 0) slot_token[e * CAPC + s] = (a < N_TOK) ? a : (a - N_TOK);
  }
}

// ---------------------------------------------------------------------------
// K5: dispatch — exp_in row = bf16(x[token]) for used slots only.
// ---------------------------------------------------------------------------
__global__ __launch_bounds__(256)
void dispatch_kernel(const float* __restrict__ x, const int* __restrict__ slot_token,
                     const int* __restrict__ ecnt, __hip_bfloat16* __restrict__ xin)
{
  const int wv = threadIdx.x >> 6, lane = threadIdx.x & 63;
  const int s = blockIdx.x * 4 + wv;
  const int e = s >> 11;                 // CAPC = 2048
  if ((s & (CAPC - 1)) >= ecnt[e]) return;
  const int n = slot_token[s];
  unsigned short* orow = (unsigned short*)xin + (size_t)s * CDIM;
  const float4* xr = (const float4*)(x + (size_t)n * CDIM);
#pragma unroll
  for (int i = 0; i < 3; ++i) {
    const float4 v = xr[i * 64 + lane];
    ushort4 o;
    o.x = f2bf(v.x); o.y = f2bf(v.y); o.z = f2bf(v.z); o.w = f2bf(v.w);
    *(ushort4*)(orow + (size_t)(i * 64 + lane) * 4) = o;
  }
}

// ---------------------------------------------------------------------------
// K6 core: 128x128-tile GEMM body, BK=64, 4 waves (2Mx2N), dbuf 64 KiB,
// counted vmcnt + counted LGKM (proven round-5/9/10/11 body).
// A: row-major [slot][K]; B: tiled [bx][kt][128][64] (16KB tiles) — same LDS
// image and swizzle as before, only the global source address map changed.
// ---------------------------------------------------------------------------
__device__ __forceinline__ void stage_a(const __hip_bfloat16* Ae, char* lds,
                                        int K, int kt, int wv, int lane)
{
  char* dst = lds + (kt & 1) * 32768;
#pragma unroll
  for (int j = 0; j < 4; ++j) {
    const int li = j * 32 + wv * 8 + (lane >> 3);
    const int kb = ((lane & 7) * 16) ^ ((li & 7) << 4);
    const char* g = (const char*)Ae + ((size_t)li * K + (size_t)kt * 64) * 2 + kb;
    __builtin_amdgcn_global_load_lds((const __attribute__((address_space(1))) unsigned int*)g,
                                     (__attribute__((address_space(3))) unsigned int*)(dst + j * 4096 + wv * 1024),
                                     16, 0, 0);
  }
}
__device__ __forceinline__ void stage_b(const char* BeT, char* lds,
                                        int kt, int wv, int lane)
{
  char* dst = lds + (kt & 1) * 32768 + 16384;
#pragma unroll
  for (int j = 0; j < 4; ++j) {
    const int li = j * 32 + wv * 8 + (lane >> 3);
    const int kb = ((lane & 7) * 16) ^ ((li & 7) << 4);
    const char* g = BeT + (size_t)kt * 16384 + li * 128 + kb;
    __builtin_amdgcn_global_load_lds((const __attribute__((address_space(1))) unsigned int*)g,
                                     (__attribute__((address_space(3))) unsigned int*)(dst + j * 4096 + wv * 1024),
                                     16, 0, 0);
  }
}

template<int VME, bool S2>
__device__ __forceinline__ void ktile2(int kt, char* lds,
                                       const __hip_bfloat16* Ae, const char* BeT,
                                       int K, floatx4 (&acc)[4][4],
                                       int wm, int wn, int fr, int fk, int wv, int lane)
{
  if constexpr (VME == 8) VMCNT(8); else VMCNT(0);
  __builtin_amdgcn_s_barrier();
  SB0();
  const char* bufA = lds + ((kt & 1) ? 32768 : 0);
  const char* bufB = bufA + 16384;
  short8 a[4][2], b[4][2];
#pragma unroll
  for (int mi = 0; mi < 4; ++mi) {
    const int lr = wm * 64 + mi * 16 + fr;
    a[mi][0] = *(const short8*)(bufA + lr * 128 + ((fk * 16) ^ ((lr & 7) << 4)));
  }
#pragma unroll
  for (int ni = 0; ni < 4; ++ni) {
    const int lj = wn * 64 + ni * 16 + fr;
    b[ni][0] = *(const short8*)(bufB + lj * 128 + ((fk * 16) ^ ((lj & 7) << 4)));
  }
  SB0();
#pragma unroll
  for (int mi = 0; mi < 4; ++mi) {
    const int lr = wm * 64 + mi * 16 + fr;
    a[mi][1] = *(const short8*)(bufA + lr * 128 + ((64 + fk * 16) ^ ((lr & 7) << 4)));
  }
#pragma unroll
  for (int ni = 0; ni < 4; ++ni) {
    const int lj = wn * 64 + ni * 16 + fr;
    b[ni][1] = *(const short8*)(bufB + lj * 128 + ((64 + fk * 16) ^ ((lj & 7) << 4)));
  }
  SB0();
  LGKM(8); SB0();
  __builtin_amdgcn_s_setprio(1);
#pragma unroll
  for (int mi = 0; mi < 4; ++mi)
#pragma unroll
    for (int ni = 0; ni < 4; ++ni)
      acc[mi][ni] = __builtin_amdgcn_mfma_f32_16x16x32_bf16(a[mi][0], b[ni][0], acc[mi][ni], 0, 0, 0);
  __builtin_amdgcn_s_setprio(0);
  SB0();
  LGKM(0); SB0();
  __builtin_amdgcn_s_setprio(1);
#pragma unroll
  for (int mi = 0; mi < 4; ++mi)
#pragma unroll
    for (int ni = 0; ni < 4; ++ni)
      acc[mi][ni] = __builtin_amdgcn_mfma_f32_16x16x32_bf16(a[mi][1], b[ni][1], acc[mi][ni], 0, 0, 0);
  __builtin_amdgcn_s_setprio(0);
  SB0();
  __builtin_amdgcn_s_barrier();
  if (S2) {
    stage_a(Ae, lds, K, kt + 2, wv, lane);
    stage_b(BeT, lds, kt + 2, wv, lane);
  }
  SB0();
}

// fast exact-grade GELU: tanh form, |err| ~3e-4 << bf16 rounding of the output
static __device__ __forceinline__ float gelu_fast(float v) {
  const float u2 = v * (1.5957691216f + 0.0713548163f * v * v);
  const float ez = __expf(u2);
  return v * ez / (ez + 1.0f);
}

// Shared epilogue: LDS-staged coalesced bf16 store (wave-private 2KB region).
template<int EPI>
__device__ __forceinline__ void epilogue_bf16(floatx4 (&acc)[4][4], char* lds,
                                              const float* be, unsigned short* Cb,
                                              int Nn, int m0, int n0,
                                              int wm, int wn, int fr, int fk,
                                              int wv, int lane)
{
  unsigned short* ep = (unsigned short*)(lds + wv * 2048);
  float bcol[4];
#pragma unroll
  for (int ni = 0; ni < 4; ++ni) bcol[ni] = be[n0 + wn * 64 + ni * 16 + fr];
#pragma unroll
  for (int mi = 0; mi < 4; ++mi) {
#pragma unroll
    for (int ni = 0; ni < 4; ++ni)
#pragma unroll
      for (int j = 0; j < 4; ++j) {
        float v = acc[mi][ni][j] + bcol[ni];
        if (EPI == 1) v = gelu_fast(v);
        const int row = fk * 4 + j;
        *(unsigned short*)((char*)ep + row * 128 + ((ni * 32 + fr * 2) ^ (fk << 5))) = f2bf(v);
      }
    LGKM(0); SB0();
    const int r = lane & 15;
    const int grow = m0 + wm * 64 + mi * 16 + r;
#pragma unroll
    for (int it = 0; it < 2; ++it) {
      const int q = (lane >> 4) + it * 4;
      const short8 vv = *(const short8*)((char*)ep + r * 128 + ((q * 16) ^ ((r >> 2) << 5)));
      *(short8*)(Cb + (size_t)grow * Nn + n0 + wn * 64 + q * 8) = vv;
    }
    LGKM(0); SB0();
  }
}

// ---------------------------------------------------------------------------
// K6a: GEMM1 persistent — grid 512 (2 blocks/CU); each block loops over its
// XCD-chunked share of the work list.  B tiled: [e][bx<24][kt<12][128][64].
// ---------------------------------------------------------------------------
__global__ __launch_bounds__(256, 2)
void gemm1p(const __hip_bfloat16* __restrict__ A, const __hip_bfloat16* __restrict__ Bt,
            const float* __restrict__ bias, __hip_bfloat16* __restrict__ Cout,
            const int* __restrict__ work, const int* __restrict__ wcnt)
{
  extern __shared__ __align__(16) char lds[];
  const int T = wcnt[0];
  const int cpx = (T + 7) >> 3;
  const int x8 = blockIdx.x & 7, l = blockIdx.x >> 3;
  const int lim = (x8 + 1) * cpx < T ? (x8 + 1) * cpx : T;

  const int t = threadIdx.x, wv = t >> 6, lane = t & 63;
  const int wm = wv >> 1, wn = wv & 1;
  const int fr = lane & 15, fk = lane >> 4;
  constexpr int ntk = CDIM / 64;   // 12

  for (int i = x8 * cpx + l; i < lim; i += 64) {
    const int p = i / 24;
    const int bx0 = i % 24;
    const int bx = (p & 1) ? (23 - bx0) : bx0;          // serpentine for L2 reuse
    const int w = work[p];
    const int e = w >> 8, by = w & 255;

    const __hip_bfloat16* Ae = A + (size_t)e * CAPC * CDIM + (size_t)by * 128 * CDIM;
    const char* BeT = (const char*)Bt + (((size_t)e * 24 + bx) * 12) * 16384;

    floatx4 acc[4][4] = {};

    stage_a(Ae, lds, CDIM, 0, wv, lane);
    stage_b(BeT, lds, 0, wv, lane);
    stage_a(Ae, lds, CDIM, 1, wv, lane);
    stage_b(BeT, lds, 1, wv, lane);
    SB0();

#pragma unroll 1
    for (int kt = 0; kt < ntk - 2; ++kt)
      ktile2<8, true>(kt, lds, Ae, BeT, CDIM, acc, wm, wn, fr, fk, wv, lane);
    ktile2<8, false>(ntk - 2, lds, Ae, BeT, CDIM, acc, wm, wn, fr, fk, wv, lane);
    ktile2<0, false>(ntk - 1, lds, Ae, BeT, CDIM, acc, wm, wn, fr, fk, wv, lane);

    epilogue_bf16<1>(acc, lds,
                     bias + (size_t)e * HDIM,
                     (unsigned short*)Cout + (size_t)e * CAPC * HDIM,
                     HDIM, by * 128, bx * 128, wm, wn, fr, fk, wv, lane);
    __builtin_amdgcn_s_barrier();   // all waves done with LDS epilogue regions
    SB0();
  }
}

// ---------------------------------------------------------------------------
// K6b: GEMM2 — single round; B tiled: [e][bx<6][kt<48][128][64].
// ---------------------------------------------------------------------------
__global__ __launch_bounds__(256, 2)
void gemm2x(const __hip_bfloat16* __restrict__ A, const __hip_bfloat16* __restrict__ Bt,
            const float* __restrict__ bias, __hip_bfloat16* __restrict__ Cout,
            const int* __restrict__ work, const int* __restrict__ wcnt)
{
  extern __shared__ __align__(16) char lds[];
  const int T = wcnt[1];
  const int bId = blockIdx.x;
  const int cpx = (T + 7) >> 3;
  if ((bId >> 3) >= cpx) return;
  const int idx = (bId & 7) * cpx + (bId >> 3);
  if (idx >= T) return;
  const int p = idx / 6;
  const int bx0 = idx % 6;
  const int bx = (p & 1) ? (5 - bx0) : bx0;
  const int w = work[p];
  const int e = w >> 8, by = w & 255;

  const int t = threadIdx.x, wv = t >> 6, lane = t & 63;
  const int wm = wv >> 1, wn = wv & 1;
  const int fr = lane & 15, fk = lane >> 4;
  constexpr int ntk = HDIM / 64;   // 48

  const __hip_bfloat16* Ae = A + (size_t)e * CAPC * HDIM + (size_t)by * 128 * HDIM;
  const char* BeT = (const char*)Bt + (((size_t)e * 6 + bx) * 48) * 16384;

  floatx4 acc[4][4] = {};

  stage_a(Ae, lds, HDIM, 0, wv, lane);
  stage_b(BeT, lds, 0, wv, lane);
  stage_a(Ae, lds, HDIM, 1, wv, lane);
  stage_b(BeT, lds, 1, wv, lane);
  SB0();

#pragma unroll 1
  for (int kt = 0; kt < ntk - 2; ++kt)
    ktile2<8, true>(kt, lds, Ae, BeT, HDIM, acc, wm, wn, fr, fk, wv, lane);
  ktile2<8, false>(ntk - 2, lds, Ae, BeT, HDIM, acc, wm, wn, fr, fk, wv, lane);
  ktile2<0, false>(ntk - 1, lds, Ae, BeT, HDIM, acc, wm, wn, fr, fk, wv, lane);

  epilogue_bf16<2>(acc, lds,
                   bias + (size_t)e * CDIM,
                   (unsigned short*)Cout + (size_t)e * CAPC * CDIM,
                   CDIM, by * 128, bx * 128, wm, wn, fr, fk, wv, lane);
}

// ---------------------------------------------------------------------------
// K7: combine — out[n] = w0*exp_out[e0][s0] + w1*exp_out[e1][s1], bf16 eout.
// ---------------------------------------------------------------------------
__global__ __launch_bounds__(256)
void combine_kernel(const __hip_bfloat16* __restrict__ eout, const int* __restrict__ eidx,
                    const float* __restrict__ pval, const int* __restrict__ slot,
                    float* __restrict__ out)
{
  const int wv = threadIdx.x >> 6, lane = threadIdx.x & 63;
  const int n = blockIdx.x * 4 + wv;
  const int e0 = eidx[n], e1 = eidx[N_TOK + n];
  int s0 = slot[n], s1 = slot[N_TOK + n];
  const float w0 = (s0 >= 0) ? pval[n] : 0.f;
  const float w1 = (s1 >= 0) ? pval[N_TOK + n] : 0.f;
  s0 = (s0 >= 0) ? s0 : 0;
  s1 = (s1 >= 0) ? s1 : 0;
  const ushort4* r0 = (const ushort4*)((const unsigned short*)eout + ((size_t)e0 * CAPC + s0) * CDIM);
  const ushort4* r1 = (const ushort4*)((const unsigned short*)eout + ((size_t)e1 * CAPC + s1) * CDIM);
  float4* o = (float4*)(out + (size_t)n * CDIM);
#pragma unroll
  for (int i = 0; i < 3; ++i) {
    const ushort4 a = r0[i * 64 + lane];
    const ushort4 b = r1[i * 64 + lane];
    float4 c;
    c.x = w0 * bf2f(a.x) + w1 * bf2f(b.x);
    c.y = w0 * bf2f(a.y) + w1 * bf2f(b.y);
    c.z = w0 * bf2f(a.z) + w1 * bf2f(b.z);
    c.w = w0 * bf2f(a.w) + w1 * bf2f(b.w);
    o[i * 64 + lane] = c;
  }
}

// ---------------------------------------------------------------------------
extern "C" void kernel_launch(void* const* d_in, const int* in_sizes, int n_in,
                              void* d_out, int out_size, void* d_ws, size_t ws_size,
                              hipStream_t stream)
{
  const float* x   = (const float*)d_in[0];
  const float* wg  = (const float*)d_in[1];
  const float* cfc = (const float*)d_in[2];
  const float* fcb = (const float*)d_in[3];
  const float* cpr = (const float*)d_in[4];
  const float* prb = (const float*)d_in[5];
  float* out = (float*)d_out;

  char* ws = (char*)d_ws;
  size_t off = 0;
  auto take = [&](size_t bytes) -> void* {
    void* p = ws + off;
    off += (bytes + 255) & ~(size_t)255;
    return p;
  };
  __hip_bfloat16* wfcT = (__hip_bfloat16*)take((size_t)E_EXP * HDIM * CDIM * 2); // tiled [e][24][12][128][64]
  __hip_bfloat16* wprT = (__hip_bfloat16*)take((size_t)E_EXP * CDIM * HDIM * 2); // tiled [e][6][48][128][64]
  __hip_bfloat16* xin  = (__hip_bfloat16*)take((size_t)E_EXP * CAPC * CDIM * 2); // [E][CAP][768]
  __hip_bfloat16* hbuf = (__hip_bfloat16*)take((size_t)E_EXP * CAPC * HDIM * 2); // [E][CAP][3072]
  __hip_bfloat16* eout = (__hip_bfloat16*)take((size_t)E_EXP * CAPC * CDIM * 2); // [E][CAP][768] bf16
  int*   eidx = (int*)take((size_t)2 * N_TOK * 4);
  float* pv   = (float*)take((size_t)2 * N_TOK * 4);
  int*   slot = (int*)take((size_t)2 * N_TOK * 4);
  int*   stok = (int*)take((size_t)E_EXP * CAPC * 4);
  int*   ecnt = (int*)take((size_t)E_EXP * 4);
  int*   work2 = (int*)take((size_t)128 * 4);
  int*   wcnt = (int*)take((size_t)2 * 4);

  hipFuncSetAttribute((const void*)gemm1p,
                      hipFuncAttributeMaxDynamicSharedMemorySize, 65536);
  hipFuncSetAttribute((const void*)gemm2x,
                      hipFuncAttributeMaxDynamicSharedMemorySize, 65536);

  // fused prep: tiled weight transposes + router
  prep_kernel<<<4608 + 1024, 256, 0, stream>>>(cfc, cpr, wfcT, wprT, x, wg, eidx, pv);
  scan_kernel<<<1, 256, 0, stream>>>(eidx, slot, stok, ecnt, work2, wcnt);
  dispatch_kernel<<<(E_EXP * CAPC) / 4, 256, 0, stream>>>(x, stok, ecnt, xin);

  // GEMM1 + bias + GELU -> h (bf16): persistent 512 blocks (2/CU), work-looped.
  gemm1p<<<512, 256, 65536, stream>>>(xin, wfcT, fcb, hbuf, work2, wcnt);
  // GEMM2 + bias -> eout (bf16): single round, <=768 active blocks.
  gemm2x<<<768, 256, 65536, stream>>>(hbuf, wprT, prb, eout, work2, wcnt);

  combine_kernel<<<N_TOK / 4, 256, 0, stream>>>(eout, eidx, pv, slot, out);
}